// Round 16
// baseline (519.746 us; speedup 1.0000x reference)
//
#include <hip/hip_runtime.h>
#include <hip/hip_bf16.h>

// ---- problem constants ----
#define BSZ 4
#define TT 64
#define NNODE 128
#define NFEAT 16
#define HIDD 64
#define NHEAD 4
#define RHID 256
#define LDIM 64
#define EPG 1024
#define NGRAPH (BSZ*TT)          // 256
#define NTOT (NGRAPH*NNODE)      // 32768
#define ESLOTS (EPG+NNODE)       // 1152

// ---- canonical fp32 weight buffer offsets (floats) ----
#define WOFF_G0W 0
#define WOFF_G0AS 4096
#define WOFF_G0AD 4352
#define WOFF_G0B 4608
#define WOFF_G1W 4864
#define WOFF_G1AS 70400
#define WOFF_G1AD 70656
#define WOFF_G1B 70912
#define WOFF_G2W 71168
#define WOFF_G2AS 87552
#define WOFF_G2AD 87616
#define WOFF_G2B 87680
#define WOFF_WIHF 87744
#define WOFF_WHHF 153280
#define WOFF_BIHF 415424
#define WOFF_BHHF 416448
#define WOFF_WIHB 417472
#define WOFF_WHHB 483008
#define WOFF_BIHB 745152
#define WOFF_BHHB 746176
#define WOFF_MUW 747200
#define WOFF_MUB 779968
#define WOFF_LVW 780032
#define WOFF_LVB 812800
#define WTOTAL   812864

// ---- workspace float offsets ----
#define FOFF_WBUF 4096
#define FOFF_CSR  1052672      // csr_row int[132] then csr_src u16[1152] (as 576 ints)
#define FOFF_SYNC 1314816      // HX: 2*3*4*512 uints (sentinel protocol)
#define FOFF_WE   1576960      // WT (f16-pair Whh, 262144 uints)
#define FOFF_BBF  1900000      // bf16 B matrices (u16 view)
#define FOFF_XFP  2756608
#define FOFF_XBP  3018752
#define FOFF_HT   3280896
#define FOFF_XSEQ 3282944
#define FOFF_PA   3291136      // P0 [32768][256] bf16
#define FOFF_PB   5388288      // P1 [32768][256] bf16
#define FOFF_P    7485440      // X  [32768][16]  bf16

// bf16 B-matrix u16 offsets inside BBF (G0/G1/G2 stored TRANSPOSED [out][in])
#define BOFF_G0 0
#define BOFF_G1 4096
#define BOFF_G2 69632
#define BOFF_WF 86016
#define BOFF_WB 151552
#define BTOTAL  217088

// setup phases
#define SP_CVTX  (WTOTAL + BTOTAL)            // 1029952
#define SP_WHH   (SP_CVTX + NTOT*NFEAT)       // 1554240
#define SP_HX    (SP_WHH + 262144)            // 1816384
#define SP_TOTAL (SP_HX + 12288)              // 1828672

#define SENT 0xFFFFFFFFu

typedef __attribute__((ext_vector_type(8))) short short8;
typedef __attribute__((ext_vector_type(4))) float float4v;

__device__ __forceinline__ float b2f(unsigned short u){
  union { unsigned int i; float f; } v; v.i = ((unsigned int)u) << 16; return v.f;
}
__device__ __forceinline__ unsigned short f2b(float f){
  __hip_bfloat16 h = __float2bfloat16(f);
  union { __hip_bfloat16 h; unsigned short u; } v; v.h = h; return v.u;
}
__device__ __forceinline__ float ldf(const void* p, int i, int flag){
  return flag ? b2f(((const unsigned short*)p)[i]) : ((const float*)p)[i];
}
__device__ __forceinline__ float h2f(unsigned short s){
  union { _Float16 hh; unsigned short s; } u; u.s = s; return (float)u.hh;
}
__device__ __forceinline__ unsigned short f2h(float f){
  union { _Float16 hh; unsigned short s; } u; u.hh = (_Float16)f; return u.s;
}

// fused half2 dot: acc += w.x*h.x + w.y*h.y
__device__ __forceinline__ float dot2h(unsigned int w, unsigned int h, float acc){
#if __has_builtin(__builtin_amdgcn_fdot2)
  typedef _Float16 h2v __attribute__((ext_vector_type(2)));
  union { unsigned int u; h2v v; } a, b; a.u = w; b.u = h;
  return __builtin_amdgcn_fdot2(a.v, b.v, acc, false);
#else
  union { unsigned int u; _Float16 h[2]; } a, b; a.u = w; b.u = h;
  return acc + (float)a.h[0] * (float)b.h[0] + (float)a.h[1] * (float)b.h[1];
#endif
}

// ---------------- dtype sniff ----------------
__global__ void sniff_kernel(const unsigned short* __restrict__ w, int* __restrict__ flag){
  __shared__ int cnt;
  if (threadIdx.x == 0) cnt = 0;
  __syncthreads();
  int ok = 0;
  for (int i = threadIdx.x; i < 2048; i += 256){
    float a = fabsf(b2f(w[2 * i]));
    if (a > 1e-8f && a < 4.f) ok++;
  }
  atomicAdd(&cnt, ok);
  __syncthreads();
  if (threadIdx.x == 0) *flag = (cnt >= 1024) ? 1 : 0;
}

// ---------------- fused setup: cvtw + packb(T) + cvtx + packwhh + HX init + CSR ----------------
struct CvtArgs {
  const void* src[24];
  int off[25];
};
__global__ void setup_kernel(CvtArgs a, const int* __restrict__ flag,
                             float* __restrict__ W, unsigned short* __restrict__ BBF,
                             unsigned short* __restrict__ P, unsigned int* __restrict__ WT,
                             unsigned int* __restrict__ HX,
                             const void* __restrict__ x, const int* __restrict__ ei,
                             int* __restrict__ csr_row, unsigned short* __restrict__ csr_src)
{
  __shared__ int cnt[NNODE];
  __shared__ int off[NNODE];
  __shared__ int wo[NNODE];
  const int tid = threadIdx.x;

  if (blockIdx.x == gridDim.x - 1){
    // ---- CSR build with parallel scan ----
    if (tid < NNODE) cnt[tid] = 0;
    __syncthreads();
    for (int i = tid; i < ESLOTS; i += 256){
      int d = (i < EPG) ? ei[EPG + i] : (i - EPG);
      atomicAdd(&cnt[d], 1);
    }
    __syncthreads();
    if (tid < NNODE) off[tid] = cnt[tid];
    for (int o = 1; o < NNODE; o <<= 1){
      __syncthreads();
      int t = (tid < NNODE && tid >= o) ? off[tid - o] : 0;
      __syncthreads();
      if (tid < NNODE) off[tid] += t;
    }
    __syncthreads();                       // off = inclusive scan
    if (tid < NNODE){
      wo[tid] = off[tid] - cnt[tid];       // exclusive
      csr_row[tid + 1] = off[tid];
    }
    if (tid == 0) csr_row[0] = 0;
    __syncthreads();
    for (int i = tid; i < ESLOTS; i += 256){
      int s, d;
      if (i < EPG){ s = ei[i]; d = ei[EPG + i]; } else { s = i - EPG; d = i - EPG; }
      int pos = atomicAdd(&wo[d], 1);
      csr_src[pos] = (unsigned short)s;
    }
    return;
  }

  int id = blockIdx.x * blockDim.x + tid;
  if (id >= SP_TOTAL) return;
  int fl = *flag;
  if (id < WTOTAL){
    int k = 0;
    while (id >= a.off[k + 1]) ++k;
    W[id] = ldf(a.src[k], id - a.off[k], fl);
  } else if (id < WTOTAL + BTOTAL){
    int r = id - WTOTAL;
    float v;
    if (r < BOFF_G1){                       // G0^T [256 out][16 in]
      int o = r >> 4, k = r & 15;
      v = ldf(a.src[0], k * 256 + o, fl);
    } else if (r < BOFF_G2){                // G1^T [256 out][256 in]
      int rr = r - BOFF_G1; int o = rr >> 8, k = rr & 255;
      v = ldf(a.src[4], k * 256 + o, fl);
    } else if (r < BOFF_WF){                // G2^T [64 out][256 in]
      int rr = r - BOFF_G2; int o = rr >> 8, k = rr & 255;
      v = ldf(a.src[8], k * 64 + o, fl);
    } else if (r < BOFF_WB){                // WF [64 k][1024 n] (unchanged)
      int q = r - BOFF_WF; int k = q >> 10, n = q & 1023;
      v = ldf(a.src[12], n * 64 + k, fl);
    } else {
      int q = r - BOFF_WB; int k = q >> 10, n = q & 1023;
      v = ldf(a.src[16], n * 64 + k, fl);
    }
    BBF[r] = f2b(v);
  } else if (id < SP_CVTX + NTOT * NFEAT){
    int r = id - SP_CVTX;
    P[r] = fl ? ((const unsigned short*)x)[r] : f2b(((const float*)x)[r]);
  } else if (id < SP_HX){
    int r0 = id - SP_WHH;                 // < 262144
    int d = r0 >> 17;
    int r = r0 & 131071;
    int c = r & 3;
    int u = (r >> 2) & 1023;
    int kk4 = r >> 12;
    int kk = kk4 * 4 + c;
    const void* Wsrc = d ? a.src[17] : a.src[13];
    _Float16 va = (_Float16)ldf(Wsrc, u * RHID + 2 * kk, fl);
    _Float16 vb = (_Float16)ldf(Wsrc, u * RHID + 2 * kk + 1, fl);
    union { _Float16 h; unsigned short s; } ua, ub; ua.h = va; ub.h = vb;
    WT[r0] = (unsigned int)ua.s | ((unsigned int)ub.s << 16);
  } else {
    HX[id - SP_HX] = SENT;
  }
}

// ---------------- GAT layer (4-head, feature-half split): 512 blocks ----------------
// block = (graph g, half hb): computes h cols [hb*128, hb*128+128) = 2 heads,
// full attn+softmax+agg for those heads, writes P'[:, half] to global.
template<int KV>
__global__ __launch_bounds__(256)
void glayer_kernel(const unsigned short* __restrict__ Pin,
                   const unsigned short* __restrict__ BT,
                   const float* __restrict__ Wbuf,
                   int asoff, int adoff, int boff,
                   const int* __restrict__ csr_row, const unsigned short* __restrict__ csr_src,
                   unsigned short* __restrict__ Pout)
{
  __shared__ unsigned short HAs[128 * 136];    // h half, [node][col] 34,816 B
  __shared__ unsigned short Bst[128 * 40];     // 10,240 B
  __shared__ unsigned char  AWs[1152 * 2];     //  2,304 B (u8 alpha x 2 local heads)
  __shared__ unsigned short ALSs[256];         // f16 [node][2]
  __shared__ unsigned short ALDs[256];
  __shared__ int   rowL[132];
  __shared__ unsigned char srcL[1152];

  const int tid = threadIdx.x;
  const int g = blockIdx.x >> 1, hb = blockIdx.x & 1;
  const int c0 = hb * 128;
  const int w = tid >> 6, lane = tid & 63, q = lane >> 4, r = lane & 15;

  for (int i = tid; i < 129; i += 256) rowL[i] = csr_row[i];
  for (int i = tid; i < 1152; i += 256) srcL[i] = (unsigned char)csr_src[i];

  //======== GEMM: h[:, c0..c0+128) = P @ W[:, c0..] via W^T rows ========
  float4v acc0[8], acc1[8];
  #pragma unroll
  for (int i = 0; i < 8; ++i){ acc0[i] = (float4v){0,0,0,0}; acc1[i] = (float4v){0,0,0,0}; }
  const int KR = (KV + 31) / 32;
  for (int kr = 0; kr < KR; ++kr){
    const int kc = kr * 32;
    __syncthreads();
    { // stage W^T rows [c0..c0+128) x [kc..kc+32): vectorized
      int n = tid >> 1, kb = (tid & 1) * 16;
      uint4 z = {0,0,0,0}; uint4 v0 = z, v1 = z;
      if (kb < KV)     v0 = *(const uint4*)(BT + (size_t)(c0 + n) * KV + kc + kb);
      if (kb + 8 < KV) v1 = *(const uint4*)(BT + (size_t)(c0 + n) * KV + kc + kb + 8);
      *(uint4*)&Bst[n * 40 + kb] = v0;
      *(uint4*)&Bst[n * 40 + kb + 8] = v1;
    }
    short8 a0 = {0,0,0,0,0,0,0,0}, a1 = {0,0,0,0,0,0,0,0};
    if (KV >= 32 || q < 2){
      a0 = *(const short8*)(Pin + (size_t)(g * 128 + 16 * w       + r) * KV + kc + q * 8);
      a1 = *(const short8*)(Pin + (size_t)(g * 128 + 16 * (w + 4) + r) * KV + kc + q * 8);
    }
    __syncthreads();
    #pragma unroll
    for (int nt = 0; nt < 8; ++nt){
      short8 bf = *(const short8*)&Bst[(16 * nt + r) * 40 + q * 8];
      acc0[nt] = __builtin_amdgcn_mfma_f32_16x16x32_bf16(a0, bf, acc0[nt], 0, 0, 0);
      acc1[nt] = __builtin_amdgcn_mfma_f32_16x16x32_bf16(a1, bf, acc1[nt], 0, 0, 0);
    }
  }
  __syncthreads();
  #pragma unroll
  for (int nt = 0; nt < 8; ++nt)
    #pragma unroll
    for (int i = 0; i < 4; ++i){
      HAs[(16 * w       + q * 4 + i) * 136 + 16 * nt + r] = f2b(acc0[nt][i]);
      HAs[(16 * (w + 4) + q * 4 + i) * 136 + 16 * nt + r] = f2b(acc1[nt][i]);
    }
  __syncthreads();

  //======== attention logits (2 local heads; lane covers 2 cols) ========
  {
    float as0 = Wbuf[asoff + c0 + 2 * lane], as1 = Wbuf[asoff + c0 + 2 * lane + 1];
    float ad0 = Wbuf[adoff + c0 + 2 * lane], ad1 = Wbuf[adoff + c0 + 2 * lane + 1];
    for (int it = 0; it < 32; ++it){
      int n = it * 4 + w;
      float e0 = b2f(HAs[n * 136 + 2 * lane]);
      float e1 = b2f(HAs[n * 136 + 2 * lane + 1]);
      float vs = e0 * as0 + e1 * as1;
      float vd = e0 * ad0 + e1 * ad1;
      #pragma unroll
      for (int m = 16; m >= 1; m >>= 1){ vs += __shfl_xor(vs, m); vd += __shfl_xor(vd, m); }
      if ((lane & 31) == 0){
        ALSs[n * 2 + (lane >> 5)] = f2h(vs);
        ALDs[n * 2 + (lane >> 5)] = f2h(vd);
      }
    }
  }
  __syncthreads();

  //======== softmax -> u8 alpha (256 jobs = 128 dst x 2 local heads) ========
  {
    int n = tid >> 1, hl = tid & 1;
    float aldv = h2f(ALDs[n * 2 + hl]);
    int rs = rowL[n], re = rowL[n + 1];
    float mx = -3e38f, den = 0.f;
    for (int j = rs; j < re; ++j){
      float v = h2f(ALSs[srcL[j] * 2 + hl]) + aldv;
      v = v > 0.f ? v : 0.2f * v;
      if (v > mx){ den = den * __expf(mx - v) + 1.f; mx = v; }
      else den += __expf(v - mx);
    }
    float iden = 1.f / (den + 1e-16f);
    for (int j = rs; j < re; ++j){
      float v = h2f(ALSs[srcL[j] * 2 + hl]) + aldv;
      v = v > 0.f ? v : 0.2f * v;
      float al = __expf(v - mx) * iden;
      AWs[j * 2 + hl] = (unsigned char)(al * 255.f + 0.5f);
    }
  }
  __syncthreads();

  //======== aggregate + bias + relu -> Pout global ========
  {
    int hl = lane >> 5;
    int fl = 2 * lane;                     // local col pair
    float bz0 = Wbuf[boff + c0 + fl], bz1 = Wbuf[boff + c0 + fl + 1];
    for (int n = w; n < 128; n += 4){
      int rs = rowL[n], re = rowL[n + 1];
      float A0 = 0.f, A1 = 0.f;
      for (int j = rs; j < re; j += 4){
        int cnt = re - j;
        int i1 = j + (cnt > 1 ? 1 : 0);
        int i2 = j + (cnt > 2 ? 2 : 0);
        int i3 = j + (cnt > 3 ? 3 : 0);
        int s0 = srcL[j], s1 = srcL[i1], s2 = srcL[i2], s3 = srcL[i3];
        float w0 = AWs[j * 2 + hl] * (1.f / 255.f);
        float w1 = cnt > 1 ? AWs[i1 * 2 + hl] * (1.f / 255.f) : 0.f;
        float w2 = cnt > 2 ? AWs[i2 * 2 + hl] * (1.f / 255.f) : 0.f;
        float w3 = cnt > 3 ? AWs[i3 * 2 + hl] * (1.f / 255.f) : 0.f;
        const unsigned short* p0 = &HAs[s0 * 136 + fl];
        const unsigned short* p1 = &HAs[s1 * 136 + fl];
        const unsigned short* p2 = &HAs[s2 * 136 + fl];
        const unsigned short* p3 = &HAs[s3 * 136 + fl];
        A0 += w0 * b2f(p0[0]) + w1 * b2f(p1[0]) + w2 * b2f(p2[0]) + w3 * b2f(p3[0]);
        A1 += w0 * b2f(p0[1]) + w1 * b2f(p1[1]) + w2 * b2f(p2[1]) + w3 * b2f(p3[1]);
      }
      A0 += bz0; A1 += bz1;
      unsigned short o0 = f2b(A0 > 0.f ? A0 : 0.f);
      unsigned short o1 = f2b(A1 > 0.f ? A1 : 0.f);
      unsigned int pk = (unsigned int)o0 | ((unsigned int)o1 << 16);
      *(unsigned int*)&Pout[(size_t)(g * 128 + n) * 256 + c0 + fl] = pk;
    }
  }
}

// ---------------- GAT layer 2 (1 head, HD=64) + pool: 512 blocks (split agg/pool by half) ----------------
__global__ __launch_bounds__(256)
void glayer2_kernel(const unsigned short* __restrict__ Pin,
                    const unsigned short* __restrict__ BT,
                    const float* __restrict__ Wbuf,
                    const int* __restrict__ csr_row, const unsigned short* __restrict__ csr_src,
                    unsigned short* __restrict__ XSEQ)
{
  __shared__ unsigned short HAs[128 * 72];     // full h2 [node][64+pad]
  __shared__ unsigned short Bst[64 * 40];
  __shared__ unsigned short AWs[1152];         // f16 alpha (1 head)
  __shared__ float ALSs[128];
  __shared__ float ALDs[128];
  __shared__ int   rowL[132];
  __shared__ unsigned char srcL[1152];
  __shared__ float pools[8][32];

  const int tid = threadIdx.x;
  const int g = blockIdx.x >> 1, hb = blockIdx.x & 1;
  const int w = tid >> 6, lane = tid & 63, q = lane >> 4, r = lane & 15;

  for (int i = tid; i < 129; i += 256) rowL[i] = csr_row[i];
  for (int i = tid; i < 1152; i += 256) srcL[i] = (unsigned char)csr_src[i];

  //======== GEMM: h2[128][64] = P1 @ g2W (duplicated across the 2 half-blocks) ========
  float4v acc0[4], acc1[4];
  #pragma unroll
  for (int i = 0; i < 4; ++i){ acc0[i] = (float4v){0,0,0,0}; acc1[i] = (float4v){0,0,0,0}; }
  for (int kr = 0; kr < 8; ++kr){
    const int kc = kr * 32;
    __syncthreads();
    { // stage G2^T rows [0..64) x [kc..kc+32)
      int n = tid >> 2, kb = (tid & 3) * 8;
      uint4 v = *(const uint4*)(BT + (size_t)n * 256 + kc + kb);
      *(uint4*)&Bst[n * 40 + kb] = v;
    }
    short8 a0 = *(const short8*)(Pin + (size_t)(g * 128 + 16 * w       + r) * 256 + kc + q * 8);
    short8 a1 = *(const short8*)(Pin + (size_t)(g * 128 + 16 * (w + 4) + r) * 256 + kc + q * 8);
    __syncthreads();
    #pragma unroll
    for (int nt = 0; nt < 4; ++nt){
      short8 bf = *(const short8*)&Bst[(16 * nt + r) * 40 + q * 8];
      acc0[nt] = __builtin_amdgcn_mfma_f32_16x16x32_bf16(a0, bf, acc0[nt], 0, 0, 0);
      acc1[nt] = __builtin_amdgcn_mfma_f32_16x16x32_bf16(a1, bf, acc1[nt], 0, 0, 0);
    }
  }
  __syncthreads();
  #pragma unroll
  for (int nt = 0; nt < 4; ++nt)
    #pragma unroll
    for (int i = 0; i < 4; ++i){
      HAs[(16 * w       + q * 4 + i) * 72 + 16 * nt + r] = f2b(acc0[nt][i]);
      HAs[(16 * (w + 4) + q * 4 + i) * 72 + 16 * nt + r] = f2b(acc1[nt][i]);
    }
  __syncthreads();

  //======== attention (1 head, full 64 cols) ========
  {
    float asv = Wbuf[WOFF_G2AS + lane];
    float adv = Wbuf[WOFF_G2AD + lane];
    for (int it = 0; it < 32; ++it){
      int n = it * 4 + w;
      float e0 = b2f(HAs[n * 72 + lane]);
      float vs = e0 * asv, vd = e0 * adv;
      #pragma unroll
      for (int m = 32; m >= 1; m >>= 1){ vs += __shfl_xor(vs, m); vd += __shfl_xor(vd, m); }
      if (lane == 0){ ALSs[n] = vs; ALDs[n] = vd; }
    }
  }
  __syncthreads();
  if (tid < 128){
    int n = tid;
    float aldv = ALDs[n];
    int rs = rowL[n], re = rowL[n + 1];
    float mx = -3e38f, den = 0.f;
    for (int j = rs; j < re; ++j){
      float v = ALSs[srcL[j]] + aldv;
      v = v > 0.f ? v : 0.2f * v;
      if (v > mx){ den = den * __expf(mx - v) + 1.f; mx = v; }
      else den += __expf(v - mx);
    }
    float iden = 1.f / (den + 1e-16f);
    for (int j = rs; j < re; ++j){
      float v = ALSs[srcL[j]] + aldv;
      v = v > 0.f ? v : 0.2f * v;
      AWs[j] = f2h(__expf(v - mx) * iden);
    }
  }
  __syncthreads();

  //======== agg + bias + relu + pool (this block: cols [hb*32, hb*32+32)) ========
  {
    int fl = lane & 31;
    int ng = lane >> 5;
    int col = hb * 32 + fl;
    float bz = Wbuf[WOFF_G2B + col];
    float psum = 0.f;
    for (int n = w * 2 + ng; n < 128; n += 8){
      int rs = rowL[n], re = rowL[n + 1];
      float A0 = 0.f;
      for (int j = rs; j < re; j += 4){
        int cnt = re - j;
        int i1 = j + (cnt > 1 ? 1 : 0);
        int i2 = j + (cnt > 2 ? 2 : 0);
        int i3 = j + (cnt > 3 ? 3 : 0);
        int s0 = srcL[j], s1 = srcL[i1], s2 = srcL[i2], s3 = srcL[i3];
        float w0 = h2f(AWs[j]);
        float w1 = cnt > 1 ? h2f(AWs[i1]) : 0.f;
        float w2 = cnt > 2 ? h2f(AWs[i2]) : 0.f;
        float w3 = cnt > 3 ? h2f(AWs[i3]) : 0.f;
        A0 += w0 * b2f(HAs[s0 * 72 + col]) + w1 * b2f(HAs[s1 * 72 + col])
            + w2 * b2f(HAs[s2 * 72 + col]) + w3 * b2f(HAs[s3 * 72 + col]);
      }
      A0 += bz;
      psum += (A0 > 0.f ? A0 : 0.f);
    }
    pools[w * 2 + ng][fl] = psum;
  }
  __syncthreads();
  if (tid < 32){
    float s = 0.f;
    #pragma unroll
    for (int p = 0; p < 8; ++p) s += pools[p][tid];
    int b = g >> 6, tq = g & 63;
    XSEQ[(size_t)(tq * BSZ + b) * HIDD + hb * 32 + tid] = f2b(s);
  }
}

// ---------------- MFMA matmul for BOTH Wih GEMMs in one launch (z = dir) ----------------
__global__ __launch_bounds__(256)
void mmx2_kernel(const unsigned short* __restrict__ A,
                 const unsigned short* __restrict__ B0, const unsigned short* __restrict__ B1,
                 float* __restrict__ C0, float* __restrict__ C1, int M, int Nc, int K)
{
  __shared__ unsigned short As[64][40];
  __shared__ unsigned short Bs[64][40];
  const unsigned short* Bb = blockIdx.z ? B1 : B0;
  float* C = blockIdx.z ? C1 : C0;
  const int tid = threadIdx.x;
  const int w = tid >> 6, lane = tid & 63, q = lane >> 4, r = lane & 15;
  const int m0 = blockIdx.x * 64, n0 = blockIdx.y * 64;
  float4v acc0 = {0,0,0,0}, acc1 = {0,0,0,0}, acc2 = {0,0,0,0}, acc3 = {0,0,0,0};
  const int arow = tid >> 2, akb = (tid & 3) * 8;
  const int bk = tid >> 3, bnb = (tid & 7) * 8;
  for (int kc = 0; kc < K; kc += 32){
    int kw = K - kc; if (kw > 32) kw = 32;
    if (akb < kw){
      uint4 v = *(const uint4*)(A + (size_t)(m0 + arow) * K + kc + akb);
      *(uint4*)&As[arow][akb] = v;
    } else {
      uint4 z = {0,0,0,0}; *(uint4*)&As[arow][akb] = z;
    }
    if (bk < kw){
      uint4 v = *(const uint4*)(Bb + (size_t)(kc + bk) * Nc + n0 + bnb);
      const unsigned short* vs = (const unsigned short*)&v;
      #pragma unroll
      for (int e = 0; e < 8; ++e) Bs[bnb + e][bk] = vs[e];
    } else {
      #pragma unroll
      for (int e = 0; e < 8; ++e) Bs[bnb + e][bk] = 0;
    }
    __syncthreads();
    short8 af = *(const short8*)&As[16 * w + r][q * 8];
    short8 b0 = *(const short8*)&Bs[r][q * 8];
    short8 b1 = *(const short8*)&Bs[16 + r][q * 8];
    short8 b2 = *(const short8*)&Bs[32 + r][q * 8];
    short8 b3 = *(const short8*)&Bs[48 + r][q * 8];
    acc0 = __builtin_amdgcn_mfma_f32_16x16x32_bf16(af, b0, acc0, 0, 0, 0);
    acc1 = __builtin_amdgcn_mfma_f32_16x16x32_bf16(af, b1, acc1, 0, 0, 0);
    acc2 = __builtin_amdgcn_mfma_f32_16x16x32_bf16(af, b2, acc2, 0, 0, 0);
    acc3 = __builtin_amdgcn_mfma_f32_16x16x32_bf16(af, b3, acc3, 0, 0, 0);
    __syncthreads();
  }
  const int row = m0 + 16 * w + q * 4, col0 = n0 + r;
  #pragma unroll
  for (int i = 0; i < 4; ++i){
    size_t base = (size_t)(row + i) * Nc;
    C[base + col0]      = acc0[i];
    C[base + col0 + 16] = acc1[i];
    C[base + col0 + 32] = acc2[i];
    C[base + col0 + 48] = acc3[i];
  }
}

// ---------------- LSTM, M-split, sentinel-payload sync with PER-CONSUMER copies ----------------
__global__ __launch_bounds__(256)
void lstm12_kernel(const float* __restrict__ XF, const float* __restrict__ XB,
                   const unsigned int* __restrict__ WT,
                   const float* __restrict__ bih_f, const float* __restrict__ bhh_f,
                   const float* __restrict__ bih_b, const float* __restrict__ bhh_b,
                   unsigned int* __restrict__ HX,
                   float* __restrict__ HT)
{
  __shared__ unsigned int WL[32][256][4];
  __shared__ unsigned int h2u[512];
  __shared__ float glds[4][64][5];

  const int tid = threadIdx.x;
  const int m = blockIdx.x & 3, dir = blockIdx.x >> 2;
  const int gq = tid >> 6, jl = tid & 63;
  const int u = gq * 256 + 64 * m + jl;
  const float* Xp = dir ? XB : XF;
  const float bias = (dir ? bih_b : bih_f)[u] + (dir ? bhh_b : bhh_f)[u];
  const int ub = tid >> 6, uj = tid & 63;
  unsigned int* HXd = HX + dir * 6144;       // [slot:3][consumer:4][512]

  {
    const uint4* WT4 = (const uint4*)(WT + (dir << 17));
    #pragma unroll
    for (int kk4 = 0; kk4 < 32; ++kk4)
      *(uint4*)WL[kk4][tid] = WT4[(kk4 << 10) + u];
  }
  for (int i = tid; i < 512; i += 256) h2u[i] = 0;
  float c = 0.f;
  __syncthreads();

  float a0, a1, a2, a3;
  auto consume = [&](int kk4){
    uint4 w4 = *(const uint4*)WL[kk4][tid];
    uint4 hb0 = *(const uint4*)&h2u[0 * 128 + (kk4 << 2)];
    uint4 hb1 = *(const uint4*)&h2u[1 * 128 + (kk4 << 2)];
    uint4 hb2 = *(const uint4*)&h2u[2 * 128 + (kk4 << 2)];
    uint4 hb3 = *(const uint4*)&h2u[3 * 128 + (kk4 << 2)];
    a0 = dot2h(w4.x, hb0.x, a0); a0 = dot2h(w4.y, hb0.y, a0);
    a0 = dot2h(w4.z, hb0.z, a0); a0 = dot2h(w4.w, hb0.w, a0);
    a1 = dot2h(w4.x, hb1.x, a1); a1 = dot2h(w4.y, hb1.y, a1);
    a1 = dot2h(w4.z, hb1.z, a1); a1 = dot2h(w4.w, hb1.w, a1);
    a2 = dot2h(w4.x, hb2.x, a2); a2 = dot2h(w4.y, hb2.y, a2);
    a2 = dot2h(w4.z, hb2.z, a2); a2 = dot2h(w4.w, hb2.w, a2);
    a3 = dot2h(w4.x, hb3.x, a3); a3 = dot2h(w4.y, hb3.y, a3);
    a3 = dot2h(w4.z, hb3.z, a3); a3 = dot2h(w4.w, hb3.w, a3);
  };

  for (int t = 0; t < TT; ++t){
    const int tb = dir ? (TT - 1 - t) : t;
    const float* xr = Xp + (size_t)(tb * 4) * 1024 + u;
    a0 = bias + xr[0];
    a1 = bias + xr[1024];
    a2 = bias + xr[2048];
    a3 = bias + xr[3072];
    #pragma unroll
    for (int i = 0; i < 8; ++i) consume(8 * m + i);
    if (t > 0 && gq > 0){
      int qp = (m + gq) & 3;
      unsigned int* S = HXd + ((t - 1) % 3) * 2048 + m * 512;
      int b2 = jl >> 5, p2 = jl & 31;
      int i1 = b2 * 128 + 32 * qp + p2;
      int i2 = (b2 + 2) * 128 + 32 * qp + p2;
      unsigned int v1, v2;
      int guard = 0;
      while ((v1 = __hip_atomic_load(&S[i1], __ATOMIC_RELAXED, __HIP_MEMORY_SCOPE_AGENT)) == SENT
             && guard < 200000){ __builtin_amdgcn_s_sleep(1); ++guard; }
      guard = 0;
      while ((v2 = __hip_atomic_load(&S[i2], __ATOMIC_RELAXED, __HIP_MEMORY_SCOPE_AGENT)) == SENT
             && guard < 200000){ __builtin_amdgcn_s_sleep(1); ++guard; }
      h2u[i1] = v1; h2u[i2] = v2;
      __hip_atomic_store(&S[i1], SENT, __ATOMIC_RELAXED, __HIP_MEMORY_SCOPE_AGENT);
      __hip_atomic_store(&S[i2], SENT, __ATOMIC_RELAXED, __HIP_MEMORY_SCOPE_AGENT);
    }
    __syncthreads();
    #pragma unroll
    for (int i = 1; i < 4; ++i){
      int qp = (m + i) & 3;
      #pragma unroll
      for (int s = 0; s < 8; ++s) consume(8 * qp + s);
    }
    glds[gq][jl][0] = a0; glds[gq][jl][1] = a1;
    glds[gq][jl][2] = a2; glds[gq][jl][3] = a3;
    __syncthreads();

    float gi = glds[0][uj][ub];
    float gf = glds[1][uj][ub];
    float gg = glds[2][uj][ub];
    float go = glds[3][uj][ub];
    float si = 1.f / (1.f + __expf(-gi));
    float sf = 1.f / (1.f + __expf(-gf));
    float so = 1.f / (1.f + __expf(-go));
    float tg = 1.f - 2.f / (1.f + __expf(2.f * gg));
    c = sf * c + si * tg;
    float ch = 1.f - 2.f / (1.f + __expf(2.f * c));
    float hval = so * ch;
    if (t == TT - 1){
      HT[(size_t)(dir * 4 + ub) * RHID + (64 * m + uj)] = hval;
      break;
    }
    union { _Float16 h; unsigned short s; } uh; uh.h = (_Float16)hval;
    unsigned int own = uh.s;
    unsigned int partner = ((unsigned int)__shfl_xor((int)own, 1)) & 0xffffu;
    unsigned int* S = HXd + (t % 3) * 2048;
    if ((uj & 1) == 0){
      unsigned int v = own | (partner << 16);
      int p = uj >> 1;
      int idx = ub * 128 + 32 * m + p;
      h2u[idx] = v;
      #pragma unroll
      for (int cns = 1; cns < 4; ++cns)
        __hip_atomic_store(&S[((m + cns) & 3) * 512 + idx], v,
                           __ATOMIC_RELAXED, __HIP_MEMORY_SCOPE_AGENT);
    }
    __syncthreads();
  }
}

// ---------------- heads + Poincare projection, fp32 out ----------------
__global__ __launch_bounds__(512)
void head2_kernel(const float* __restrict__ HT,
                  const float* __restrict__ muW, const float* __restrict__ mub,
                  const float* __restrict__ lvW, const float* __restrict__ lvb,
                  float* __restrict__ out)
{
  __shared__ float feat[4][512];
  __shared__ float muv[4][64];
  __shared__ float lvv[4][64];
  int tid = threadIdx.x;
  for (int i = tid; i < 2048; i += 512){
    int rr = i >> 8, k = i & 255;
    int b = rr & 3, d = rr >> 2;
    feat[b][d * 256 + k] = HT[i];
  }
  __syncthreads();
  int w = tid >> 6, lane = tid & 63;
  for (int job = w; job < 512; job += 8){
    int j = job & 63, b = (job >> 6) & 3, mat = job >> 8;
    const float* W = (mat ? lvW : muW) + (size_t)j * 512;
    float s = 0.f;
    #pragma unroll
    for (int e = 0; e < 8; ++e) s += W[lane * 8 + e] * feat[b][lane * 8 + e];
    #pragma unroll
    for (int mm = 32; mm >= 1; mm >>= 1) s += __shfl_xor(s, mm);
    if (lane == 0){
      float v = s + (mat ? lvb[j] : mub[j]);
      if (mat) lvv[b][j] = v; else muv[b][j] = v;
    }
  }
  __syncthreads();
  if (tid < 256){
    int b = tid >> 6, j = tid & 63;
    float mu = muv[b][j];
    float sq = mu * mu;
    #pragma unroll
    for (int mm = 32; mm >= 1; mm >>= 1) sq += __shfl_xor(sq, mm);
    float nrm = sqrtf(sq);
    const float mxn = 1.0f - 4e-3f;
    if (nrm > mxn) mu = mu / nrm * mxn;
    out[b * 64 + j] = mu;
    out[256 + b * 64 + j] = lvv[b][j];
  }
}

extern "C" void kernel_launch(void* const* d_in, const int* in_sizes, int n_in,
                              void* d_out, int out_size, void* d_ws, size_t ws_size,
                              hipStream_t stream)
{
  const int* ei = (const int*)d_in[1];

  int*   ws_i    = (int*)d_ws;
  int*   dflag   = ws_i;
  float* FW   = (float*)d_ws;
  float* Wbuf = FW + FOFF_WBUF;
  int*   csr_row = (int*)(FW + FOFF_CSR);
  unsigned short* csr_src = (unsigned short*)(FW + FOFF_CSR + 132);
  float* XFp  = FW + FOFF_XFP;
  float* XBp  = FW + FOFF_XBP;
  float* HT   = FW + FOFF_HT;
  unsigned short* XSEQ = (unsigned short*)(FW + FOFF_XSEQ);
  unsigned short* PA   = (unsigned short*)(FW + FOFF_PA);
  unsigned short* PB   = (unsigned short*)(FW + FOFF_PB);
  unsigned short* Pb   = (unsigned short*)(FW + FOFF_P);
  unsigned int*   WT   = (unsigned int*)(FW + FOFF_WE);
  unsigned short* BBF  = (unsigned short*)(FW + FOFF_BBF);
  unsigned int*   HX   = (unsigned int*)(FW + FOFF_SYNC);

  // ---- dtype sniff + fused setup (+CSR +HX init) ----
  sniff_kernel<<<1, 256, 0, stream>>>((const unsigned short*)d_in[2], dflag);

  CvtArgs ca;
  static const int wsz[24] = {4096,256,256,256, 65536,256,256,256, 16384,64,64,64,
                              65536,262144,1024,1024, 65536,262144,1024,1024,
                              32768,64,32768,64};
  {
    int acc = 0;
    for (int k = 0; k < 24; ++k){ ca.src[k] = d_in[2 + k]; ca.off[k] = acc; acc += wsz[k]; }
    ca.off[24] = acc;
  }
  int nblk = (SP_TOTAL + 255) / 256 + 1;
  setup_kernel<<<nblk, 256, 0, stream>>>(ca, dflag, Wbuf, BBF, Pb, WT, HX,
                                         d_in[0], ei, csr_row, csr_src);

  // ---- GAT layers: 512 blocks each (graph x feature-half), 2 blocks/CU ----
  glayer_kernel<16><<<512, 256, 0, stream>>>(Pb, BBF + BOFF_G0, Wbuf,
                                             WOFF_G0AS, WOFF_G0AD, WOFF_G0B,
                                             csr_row, csr_src, PA);
  glayer_kernel<256><<<512, 256, 0, stream>>>(PA, BBF + BOFF_G1, Wbuf,
                                              WOFF_G1AS, WOFF_G1AD, WOFF_G1B,
                                              csr_row, csr_src, PB);
  glayer2_kernel<<<512, 256, 0, stream>>>(PB, BBF + BOFF_G2, Wbuf,
                                          csr_row, csr_src, XSEQ);

  // ---- LSTM input precompute: both directions in one launch ----
  mmx2_kernel<<<dim3(4, 16, 2), 256, 0, stream>>>(XSEQ, BBF + BOFF_WF, BBF + BOFF_WB,
                                                  XFp, XBp, 256, 1024, 64);

  // ---- LSTM: sentinel-payload protocol, per-consumer copies (HX pre-set to SENT by setup) ----
  lstm12_kernel<<<8, 256, 0, stream>>>(XFp, XBp, WT,
                                       Wbuf + WOFF_BIHF, Wbuf + WOFF_BHHF,
                                       Wbuf + WOFF_BIHB, Wbuf + WOFF_BHHB,
                                       HX, HT);

  // ---- heads + projection ----
  head2_kernel<<<1, 512, 0, stream>>>(HT, Wbuf + WOFF_MUW, Wbuf + WOFF_MUB,
                                      Wbuf + WOFF_LVW, Wbuf + WOFF_LVB, (float*)d_out);
}

// Round 18
// 424.757 us; speedup vs baseline: 1.2236x; 1.2236x over previous
//
#include <hip/hip_runtime.h>
#include <hip/hip_bf16.h>

// ---- problem constants ----
#define BSZ 4
#define TT 64
#define NNODE 128
#define NFEAT 16
#define HIDD 64
#define NHEAD 4
#define RHID 256
#define LDIM 64
#define EPG 1024
#define NGRAPH (BSZ*TT)          // 256
#define NTOT (NGRAPH*NNODE)      // 32768
#define ESLOTS (EPG+NNODE)       // 1152

// ---- canonical fp32 weight buffer offsets (floats) ----
#define WOFF_G0W 0
#define WOFF_G0AS 4096
#define WOFF_G0AD 4352
#define WOFF_G0B 4608
#define WOFF_G1W 4864
#define WOFF_G1AS 70400
#define WOFF_G1AD 70656
#define WOFF_G1B 70912
#define WOFF_G2W 71168
#define WOFF_G2AS 87552
#define WOFF_G2AD 87616
#define WOFF_G2B 87680
#define WOFF_WIHF 87744
#define WOFF_WHHF 153280
#define WOFF_BIHF 415424
#define WOFF_BHHF 416448
#define WOFF_WIHB 417472
#define WOFF_WHHB 483008
#define WOFF_BIHB 745152
#define WOFF_BHHB 746176
#define WOFF_MUW 747200
#define WOFF_MUB 779968
#define WOFF_LVW 780032
#define WOFF_LVB 812800
#define WTOTAL   812864

// ---- workspace float offsets ----
#define FOFF_WBUF 4096
#define FOFF_CSR  1052672      // csr_row int[132] then csr_src u16[1152]
#define FOFF_SYNC 1314816      // HX: 2*3*4*512 uints (sentinel protocol)
#define FOFF_WE   1576960      // WTB (bf16 B-frag Whh, 262144 uints)
#define FOFF_BBF  1900000      // bf16 B matrices (u16 view)
#define FOFF_XFP  2756608
#define FOFF_XBP  3018752
#define FOFF_HT   3280896
#define FOFF_XSEQ 3282944
#define FOFF_PA   3291136      // P0 [32768][256] bf16
#define FOFF_PB   5388288      // P1 [32768][256] bf16
#define FOFF_P    7485440      // X  [32768][16]  bf16

// bf16 B-matrix u16 offsets inside BBF (G0/G1/G2 stored TRANSPOSED [out][in])
#define BOFF_G0 0
#define BOFF_G1 4096
#define BOFF_G2 69632
#define BOFF_WF 86016
#define BOFF_WB 151552
#define BTOTAL  217088

// setup phases
#define SP_CVTX  (WTOTAL + BTOTAL)            // 1029952
#define SP_WHH   (SP_CVTX + NTOT*NFEAT)       // 1554240
#define SP_HX    (SP_WHH + 262144)            // 1816384
#define SP_TOTAL (SP_HX + 12288)              // 1828672

#define SENT 0xFFFFFFFFu

typedef __attribute__((ext_vector_type(8))) short short8;
typedef __attribute__((ext_vector_type(4))) float float4v;

__device__ __forceinline__ float b2f(unsigned short u){
  union { unsigned int i; float f; } v; v.i = ((unsigned int)u) << 16; return v.f;
}
__device__ __forceinline__ unsigned short f2b(float f){
  __hip_bfloat16 h = __float2bfloat16(f);
  union { __hip_bfloat16 h; unsigned short u; } v; v.h = h; return v.u;
}
__device__ __forceinline__ float ldf(const void* p, int i, int flag){
  return flag ? b2f(((const unsigned short*)p)[i]) : ((const float*)p)[i];
}
__device__ __forceinline__ float h2f(unsigned short s){
  union { _Float16 hh; unsigned short s; } u; u.s = s; return (float)u.hh;
}
__device__ __forceinline__ unsigned short f2h(float f){
  union { _Float16 hh; unsigned short s; } u; u.hh = (_Float16)f; return u.s;
}

// ---------------- dtype sniff ----------------
__global__ void sniff_kernel(const unsigned short* __restrict__ w, int* __restrict__ flag){
  __shared__ int cnt;
  if (threadIdx.x == 0) cnt = 0;
  __syncthreads();
  int ok = 0;
  for (int i = threadIdx.x; i < 2048; i += 256){
    float a = fabsf(b2f(w[2 * i]));
    if (a > 1e-8f && a < 4.f) ok++;
  }
  atomicAdd(&cnt, ok);
  __syncthreads();
  if (threadIdx.x == 0) *flag = (cnt >= 1024) ? 1 : 0;
}

// ---------------- fused setup: cvtw + packb(T) + cvtx + packwhh(MFMA B-frag) + HX + CSR ----------------
struct CvtArgs {
  const void* src[24];
  int off[25];
};
__global__ void setup_kernel(CvtArgs a, const int* __restrict__ flag,
                             float* __restrict__ W, unsigned short* __restrict__ BBF,
                             unsigned short* __restrict__ P, unsigned int* __restrict__ WT,
                             unsigned int* __restrict__ HX,
                             const void* __restrict__ x, const int* __restrict__ ei,
                             int* __restrict__ csr_row, unsigned short* __restrict__ csr_src)
{
  __shared__ int cnt[NNODE];
  __shared__ int off[NNODE];
  __shared__ int wo[NNODE];
  const int tid = threadIdx.x;

  if (blockIdx.x == gridDim.x - 1){
    // ---- CSR build with parallel scan ----
    if (tid < NNODE) cnt[tid] = 0;
    __syncthreads();
    for (int i = tid; i < ESLOTS; i += 256){
      int d = (i < EPG) ? ei[EPG + i] : (i - EPG);
      atomicAdd(&cnt[d], 1);
    }
    __syncthreads();
    if (tid < NNODE) off[tid] = cnt[tid];
    for (int o = 1; o < NNODE; o <<= 1){
      __syncthreads();
      int t = (tid < NNODE && tid >= o) ? off[tid - o] : 0;
      __syncthreads();
      if (tid < NNODE) off[tid] += t;
    }
    __syncthreads();
    if (tid < NNODE){
      wo[tid] = off[tid] - cnt[tid];
      csr_row[tid + 1] = off[tid];
    }
    if (tid == 0) csr_row[0] = 0;
    __syncthreads();
    for (int i = tid; i < ESLOTS; i += 256){
      int s, d;
      if (i < EPG){ s = ei[i]; d = ei[EPG + i]; } else { s = i - EPG; d = i - EPG; }
      int pos = atomicAdd(&wo[d], 1);
      csr_src[pos] = (unsigned short)s;
    }
    return;
  }

  int id = blockIdx.x * blockDim.x + tid;
  if (id >= SP_TOTAL) return;
  int fl = *flag;
  if (id < WTOTAL){
    int k = 0;
    while (id >= a.off[k + 1]) ++k;
    W[id] = ldf(a.src[k], id - a.off[k], fl);
  } else if (id < WTOTAL + BTOTAL){
    int r = id - WTOTAL;
    float v;
    if (r < BOFF_G1){
      int o = r >> 4, k = r & 15;
      v = ldf(a.src[0], k * 256 + o, fl);
    } else if (r < BOFF_G2){
      int rr = r - BOFF_G1; int o = rr >> 8, k = rr & 255;
      v = ldf(a.src[4], k * 256 + o, fl);
    } else if (r < BOFF_WF){
      int rr = r - BOFF_G2; int o = rr >> 8, k = rr & 255;
      v = ldf(a.src[8], k * 64 + o, fl);
    } else if (r < BOFF_WB){
      int q = r - BOFF_WF; int k = q >> 10, n = q & 1023;
      v = ldf(a.src[12], n * 64 + k, fl);
    } else {
      int q = r - BOFF_WB; int k = q >> 10, n = q & 1023;
      v = ldf(a.src[16], n * 64 + k, fl);
    }
    BBF[r] = f2b(v);
  } else if (id < SP_CVTX + NTOT * NFEAT){
    int r = id - SP_CVTX;
    P[r] = fl ? ((const unsigned short*)x)[r] : f2b(((const float*)x)[r]);
  } else if (id < SP_HX){
    // Whh -> bf16 B-fragment layout: WT[dir][m][kc][nt][lane] uint4 (pairs)
    int r0 = id - SP_WHH;                 // < 262144
    int c = r0 & 3;
    int lane = (r0 >> 2) & 63;
    int nt = (r0 >> 8) & 15;
    int kc = (r0 >> 12) & 7;
    int m = (r0 >> 15) & 3;
    int dir = r0 >> 17;
    int l = nt * 16 + (lane & 15);                 // local gate-row 0..255
    int u = (l >> 6) * 256 + 64 * m + (l & 63);    // global gate-row
    int k0 = kc * 32 + ((lane >> 4) << 3) + 2 * c; // k pair base
    const void* Wsrc = dir ? a.src[17] : a.src[13];
    unsigned short va = f2b(ldf(Wsrc, u * RHID + k0, fl));
    unsigned short vb = f2b(ldf(Wsrc, u * RHID + k0 + 1, fl));
    WT[r0] = (unsigned int)va | ((unsigned int)vb << 16);
  } else {
    HX[id - SP_HX] = SENT;
  }
}

// ---------------- GAT layer (4-head, feature-half split): 512 blocks ----------------
template<int KV>
__global__ __launch_bounds__(256)
void glayer_kernel(const unsigned short* __restrict__ Pin,
                   const unsigned short* __restrict__ BT,
                   const float* __restrict__ Wbuf,
                   int asoff, int adoff, int boff,
                   const int* __restrict__ csr_row, const unsigned short* __restrict__ csr_src,
                   unsigned short* __restrict__ Pout)
{
  __shared__ unsigned short HAs[128 * 136];
  __shared__ unsigned short Bst[128 * 40];
  __shared__ unsigned char  AWs[1152 * 2];
  __shared__ unsigned short ALSs[256];
  __shared__ unsigned short ALDs[256];
  __shared__ int   rowL[132];
  __shared__ unsigned char srcL[1152];

  const int tid = threadIdx.x;
  const int g = blockIdx.x >> 1, hb = blockIdx.x & 1;
  const int c0 = hb * 128;
  const int w = tid >> 6, lane = tid & 63, q = lane >> 4, r = lane & 15;

  for (int i = tid; i < 129; i += 256) rowL[i] = csr_row[i];
  for (int i = tid; i < 1152; i += 256) srcL[i] = (unsigned char)csr_src[i];

  float4v acc0[8], acc1[8];
  #pragma unroll
  for (int i = 0; i < 8; ++i){ acc0[i] = (float4v){0,0,0,0}; acc1[i] = (float4v){0,0,0,0}; }
  const int KR = (KV + 31) / 32;
  for (int kr = 0; kr < KR; ++kr){
    const int kc = kr * 32;
    __syncthreads();
    {
      int n = tid >> 1, kb = (tid & 1) * 16;
      uint4 z = {0,0,0,0}; uint4 v0 = z, v1 = z;
      if (kb < KV)     v0 = *(const uint4*)(BT + (size_t)(c0 + n) * KV + kc + kb);
      if (kb + 8 < KV) v1 = *(const uint4*)(BT + (size_t)(c0 + n) * KV + kc + kb + 8);
      *(uint4*)&Bst[n * 40 + kb] = v0;
      *(uint4*)&Bst[n * 40 + kb + 8] = v1;
    }
    short8 a0 = {0,0,0,0,0,0,0,0}, a1 = {0,0,0,0,0,0,0,0};
    if (KV >= 32 || q < 2){
      a0 = *(const short8*)(Pin + (size_t)(g * 128 + 16 * w       + r) * KV + kc + q * 8);
      a1 = *(const short8*)(Pin + (size_t)(g * 128 + 16 * (w + 4) + r) * KV + kc + q * 8);
    }
    __syncthreads();
    #pragma unroll
    for (int nt = 0; nt < 8; ++nt){
      short8 bf = *(const short8*)&Bst[(16 * nt + r) * 40 + q * 8];
      acc0[nt] = __builtin_amdgcn_mfma_f32_16x16x32_bf16(a0, bf, acc0[nt], 0, 0, 0);
      acc1[nt] = __builtin_amdgcn_mfma_f32_16x16x32_bf16(a1, bf, acc1[nt], 0, 0, 0);
    }
  }
  __syncthreads();
  #pragma unroll
  for (int nt = 0; nt < 8; ++nt)
    #pragma unroll
    for (int i = 0; i < 4; ++i){
      HAs[(16 * w       + q * 4 + i) * 136 + 16 * nt + r] = f2b(acc0[nt][i]);
      HAs[(16 * (w + 4) + q * 4 + i) * 136 + 16 * nt + r] = f2b(acc1[nt][i]);
    }
  __syncthreads();

  {
    float as0 = Wbuf[asoff + c0 + 2 * lane], as1 = Wbuf[asoff + c0 + 2 * lane + 1];
    float ad0 = Wbuf[adoff + c0 + 2 * lane], ad1 = Wbuf[adoff + c0 + 2 * lane + 1];
    for (int it = 0; it < 32; ++it){
      int n = it * 4 + w;
      float e0 = b2f(HAs[n * 136 + 2 * lane]);
      float e1 = b2f(HAs[n * 136 + 2 * lane + 1]);
      float vs = e0 * as0 + e1 * as1;
      float vd = e0 * ad0 + e1 * ad1;
      #pragma unroll
      for (int m = 16; m >= 1; m >>= 1){ vs += __shfl_xor(vs, m); vd += __shfl_xor(vd, m); }
      if ((lane & 31) == 0){
        ALSs[n * 2 + (lane >> 5)] = f2h(vs);
        ALDs[n * 2 + (lane >> 5)] = f2h(vd);
      }
    }
  }
  __syncthreads();

  {
    int n = tid >> 1, hl = tid & 1;
    float aldv = h2f(ALDs[n * 2 + hl]);
    int rs = rowL[n], re = rowL[n + 1];
    float mx = -3e38f, den = 0.f;
    for (int j = rs; j < re; ++j){
      float v = h2f(ALSs[srcL[j] * 2 + hl]) + aldv;
      v = v > 0.f ? v : 0.2f * v;
      if (v > mx){ den = den * __expf(mx - v) + 1.f; mx = v; }
      else den += __expf(v - mx);
    }
    float iden = 1.f / (den + 1e-16f);
    for (int j = rs; j < re; ++j){
      float v = h2f(ALSs[srcL[j] * 2 + hl]) + aldv;
      v = v > 0.f ? v : 0.2f * v;
      float al = __expf(v - mx) * iden;
      AWs[j * 2 + hl] = (unsigned char)(al * 255.f + 0.5f);
    }
  }
  __syncthreads();

  {
    int hl = lane >> 5;
    int fl = 2 * lane;
    float bz0 = Wbuf[boff + c0 + fl], bz1 = Wbuf[boff + c0 + fl + 1];
    for (int n = w; n < 128; n += 4){
      int rs = rowL[n], re = rowL[n + 1];
      float A0 = 0.f, A1 = 0.f;
      for (int j = rs; j < re; j += 4){
        int cnt2 = re - j;
        int i1 = j + (cnt2 > 1 ? 1 : 0);
        int i2 = j + (cnt2 > 2 ? 2 : 0);
        int i3 = j + (cnt2 > 3 ? 3 : 0);
        int s0 = srcL[j], s1 = srcL[i1], s2 = srcL[i2], s3 = srcL[i3];
        float w0 = AWs[j * 2 + hl] * (1.f / 255.f);
        float w1 = cnt2 > 1 ? AWs[i1 * 2 + hl] * (1.f / 255.f) : 0.f;
        float w2 = cnt2 > 2 ? AWs[i2 * 2 + hl] * (1.f / 255.f) : 0.f;
        float w3 = cnt2 > 3 ? AWs[i3 * 2 + hl] * (1.f / 255.f) : 0.f;
        const unsigned short* p0 = &HAs[s0 * 136 + fl];
        const unsigned short* p1 = &HAs[s1 * 136 + fl];
        const unsigned short* p2 = &HAs[s2 * 136 + fl];
        const unsigned short* p3 = &HAs[s3 * 136 + fl];
        A0 += w0 * b2f(p0[0]) + w1 * b2f(p1[0]) + w2 * b2f(p2[0]) + w3 * b2f(p3[0]);
        A1 += w0 * b2f(p0[1]) + w1 * b2f(p1[1]) + w2 * b2f(p2[1]) + w3 * b2f(p3[1]);
      }
      A0 += bz0; A1 += bz1;
      unsigned short o0 = f2b(A0 > 0.f ? A0 : 0.f);
      unsigned short o1 = f2b(A1 > 0.f ? A1 : 0.f);
      unsigned int pk = (unsigned int)o0 | ((unsigned int)o1 << 16);
      *(unsigned int*)&Pout[(size_t)(g * 128 + n) * 256 + c0 + fl] = pk;
    }
  }
}

// ---------------- GAT layer 2 (1 head, HD=64) + pool: 512 blocks ----------------
__global__ __launch_bounds__(256)
void glayer2_kernel(const unsigned short* __restrict__ Pin,
                    const unsigned short* __restrict__ BT,
                    const float* __restrict__ Wbuf,
                    const int* __restrict__ csr_row, const unsigned short* __restrict__ csr_src,
                    unsigned short* __restrict__ XSEQ)
{
  __shared__ unsigned short HAs[128 * 72];
  __shared__ unsigned short Bst[64 * 40];
  __shared__ unsigned short AWs[1152];
  __shared__ float ALSs[128];
  __shared__ float ALDs[128];
  __shared__ int   rowL[132];
  __shared__ unsigned char srcL[1152];
  __shared__ float pools[8][32];

  const int tid = threadIdx.x;
  const int g = blockIdx.x >> 1, hb = blockIdx.x & 1;
  const int w = tid >> 6, lane = tid & 63, q = lane >> 4, r = lane & 15;

  for (int i = tid; i < 129; i += 256) rowL[i] = csr_row[i];
  for (int i = tid; i < 1152; i += 256) srcL[i] = (unsigned char)csr_src[i];

  float4v acc0[4], acc1[4];
  #pragma unroll
  for (int i = 0; i < 4; ++i){ acc0[i] = (float4v){0,0,0,0}; acc1[i] = (float4v){0,0,0,0}; }
  for (int kr = 0; kr < 8; ++kr){
    const int kc = kr * 32;
    __syncthreads();
    {
      int n = tid >> 2, kb = (tid & 3) * 8;
      uint4 v = *(const uint4*)(BT + (size_t)n * 256 + kc + kb);
      *(uint4*)&Bst[n * 40 + kb] = v;
    }
    short8 a0 = *(const short8*)(Pin + (size_t)(g * 128 + 16 * w       + r) * 256 + kc + q * 8);
    short8 a1 = *(const short8*)(Pin + (size_t)(g * 128 + 16 * (w + 4) + r) * 256 + kc + q * 8);
    __syncthreads();
    #pragma unroll
    for (int nt = 0; nt < 4; ++nt){
      short8 bf = *(const short8*)&Bst[(16 * nt + r) * 40 + q * 8];
      acc0[nt] = __builtin_amdgcn_mfma_f32_16x16x32_bf16(a0, bf, acc0[nt], 0, 0, 0);
      acc1[nt] = __builtin_amdgcn_mfma_f32_16x16x32_bf16(a1, bf, acc1[nt], 0, 0, 0);
    }
  }
  __syncthreads();
  #pragma unroll
  for (int nt = 0; nt < 4; ++nt)
    #pragma unroll
    for (int i = 0; i < 4; ++i){
      HAs[(16 * w       + q * 4 + i) * 72 + 16 * nt + r] = f2b(acc0[nt][i]);
      HAs[(16 * (w + 4) + q * 4 + i) * 72 + 16 * nt + r] = f2b(acc1[nt][i]);
    }
  __syncthreads();

  {
    float asv = Wbuf[WOFF_G2AS + lane];
    float adv = Wbuf[WOFF_G2AD + lane];
    for (int it = 0; it < 32; ++it){
      int n = it * 4 + w;
      float e0 = b2f(HAs[n * 72 + lane]);
      float vs = e0 * asv, vd = e0 * adv;
      #pragma unroll
      for (int m = 32; m >= 1; m >>= 1){ vs += __shfl_xor(vs, m); vd += __shfl_xor(vd, m); }
      if (lane == 0){ ALSs[n] = vs; ALDs[n] = vd; }
    }
  }
  __syncthreads();
  if (tid < 128){
    int n = tid;
    float aldv = ALDs[n];
    int rs = rowL[n], re = rowL[n + 1];
    float mx = -3e38f, den = 0.f;
    for (int j = rs; j < re; ++j){
      float v = ALSs[srcL[j]] + aldv;
      v = v > 0.f ? v : 0.2f * v;
      if (v > mx){ den = den * __expf(mx - v) + 1.f; mx = v; }
      else den += __expf(v - mx);
    }
    float iden = 1.f / (den + 1e-16f);
    for (int j = rs; j < re; ++j){
      float v = ALSs[srcL[j]] + aldv;
      v = v > 0.f ? v : 0.2f * v;
      AWs[j] = f2h(__expf(v - mx) * iden);
    }
  }
  __syncthreads();

  {
    int fl = lane & 31;
    int ng = lane >> 5;
    int col = hb * 32 + fl;
    float bz = Wbuf[WOFF_G2B + col];
    float psum = 0.f;
    for (int n = w * 2 + ng; n < 128; n += 8){
      int rs = rowL[n], re = rowL[n + 1];
      float A0 = 0.f;
      for (int j = rs; j < re; j += 4){
        int cnt2 = re - j;
        int i1 = j + (cnt2 > 1 ? 1 : 0);
        int i2 = j + (cnt2 > 2 ? 2 : 0);
        int i3 = j + (cnt2 > 3 ? 3 : 0);
        int s0 = srcL[j], s1 = srcL[i1], s2 = srcL[i2], s3 = srcL[i3];
        float w0 = h2f(AWs[j]);
        float w1 = cnt2 > 1 ? h2f(AWs[i1]) : 0.f;
        float w2 = cnt2 > 2 ? h2f(AWs[i2]) : 0.f;
        float w3 = cnt2 > 3 ? h2f(AWs[i3]) : 0.f;
        A0 += w0 * b2f(HAs[s0 * 72 + col]) + w1 * b2f(HAs[s1 * 72 + col])
            + w2 * b2f(HAs[s2 * 72 + col]) + w3 * b2f(HAs[s3 * 72 + col]);
      }
      A0 += bz;
      psum += (A0 > 0.f ? A0 : 0.f);
    }
    pools[w * 2 + ng][fl] = psum;
  }
  __syncthreads();
  if (tid < 32){
    float s = 0.f;
    #pragma unroll
    for (int p = 0; p < 8; ++p) s += pools[p][tid];
    int b = g >> 6, tq = g & 63;
    XSEQ[(size_t)(tq * BSZ + b) * HIDD + hb * 32 + tid] = f2b(s);
  }
}

// ---------------- MFMA matmul for BOTH Wih GEMMs in one launch (z = dir) ----------------
__global__ __launch_bounds__(256)
void mmx2_kernel(const unsigned short* __restrict__ A,
                 const unsigned short* __restrict__ B0, const unsigned short* __restrict__ B1,
                 float* __restrict__ C0, float* __restrict__ C1, int M, int Nc, int K)
{
  __shared__ unsigned short As[64][40];
  __shared__ unsigned short Bs[64][40];
  const unsigned short* Bb = blockIdx.z ? B1 : B0;
  float* C = blockIdx.z ? C1 : C0;
  const int tid = threadIdx.x;
  const int w = tid >> 6, lane = tid & 63, q = lane >> 4, r = lane & 15;
  const int m0 = blockIdx.x * 64, n0 = blockIdx.y * 64;
  float4v acc0 = {0,0,0,0}, acc1 = {0,0,0,0}, acc2 = {0,0,0,0}, acc3 = {0,0,0,0};
  const int arow = tid >> 2, akb = (tid & 3) * 8;
  const int bk = tid >> 3, bnb = (tid & 7) * 8;
  for (int kc = 0; kc < K; kc += 32){
    int kw = K - kc; if (kw > 32) kw = 32;
    if (akb < kw){
      uint4 v = *(const uint4*)(A + (size_t)(m0 + arow) * K + kc + akb);
      *(uint4*)&As[arow][akb] = v;
    } else {
      uint4 z = {0,0,0,0}; *(uint4*)&As[arow][akb] = z;
    }
    if (bk < kw){
      uint4 v = *(const uint4*)(Bb + (size_t)(kc + bk) * Nc + n0 + bnb);
      const unsigned short* vs = (const unsigned short*)&v;
      #pragma unroll
      for (int e = 0; e < 8; ++e) Bs[bnb + e][bk] = vs[e];
    } else {
      #pragma unroll
      for (int e = 0; e < 8; ++e) Bs[bnb + e][bk] = 0;
    }
    __syncthreads();
    short8 af = *(const short8*)&As[16 * w + r][q * 8];
    short8 b0 = *(const short8*)&Bs[r][q * 8];
    short8 b1 = *(const short8*)&Bs[16 + r][q * 8];
    short8 b2 = *(const short8*)&Bs[32 + r][q * 8];
    short8 b3 = *(const short8*)&Bs[48 + r][q * 8];
    acc0 = __builtin_amdgcn_mfma_f32_16x16x32_bf16(af, b0, acc0, 0, 0, 0);
    acc1 = __builtin_amdgcn_mfma_f32_16x16x32_bf16(af, b1, acc1, 0, 0, 0);
    acc2 = __builtin_amdgcn_mfma_f32_16x16x32_bf16(af, b2, acc2, 0, 0, 0);
    acc3 = __builtin_amdgcn_mfma_f32_16x16x32_bf16(af, b3, acc3, 0, 0, 0);
    __syncthreads();
  }
  const int row = m0 + 16 * w + q * 4, col0 = n0 + r;
  #pragma unroll
  for (int i = 0; i < 4; ++i){
    size_t base = (size_t)(row + i) * Nc;
    C[base + col0]      = acc0[i];
    C[base + col0 + 16] = acc1[i];
    C[base + col0 + 32] = acc2[i];
    C[base + col0 + 48] = acc3[i];
  }
}

// ---------------- LSTM via MFMA: 8 WGs = 2 dirs x 4 unit-slices, sentinel sync ----------------
// Gates[4 batch x 1024] = A(h, 16x256 with rows 0-3 real) @ B(Whh B-frag layout).
// Per wave: 4 n-tiles x 8 k-chunks = 32 MFMA; LDS reads ~40 b128/thread/step (vs 160 scalar-dot).
__global__ __launch_bounds__(256)
void lstm13_kernel(const float* __restrict__ XF, const float* __restrict__ XB,
                   const unsigned int* __restrict__ WT,
                   const float* __restrict__ bih_f, const float* __restrict__ bhh_f,
                   const float* __restrict__ bih_b, const float* __restrict__ bhh_b,
                   unsigned int* __restrict__ HX,
                   float* __restrict__ HT)
{
  __shared__ unsigned int WL[32768];      // 128 KB: [kc][nt][lane] uint4 flat  (R17 bug: was 8192)
  __shared__ unsigned int H16[16 * 128];  // 8 KB: A rows (batch 0-3 real, 4-15 zero), bf16 pairs
  __shared__ float glds[4][256];          // gates [batch][local row]

  const int tid = threadIdx.x;
  const int m = blockIdx.x & 3, dir = blockIdx.x >> 2;
  const int w = tid >> 6, lane = tid & 63, quad = lane >> 4, r = lane & 15;
  const float* Xp = dir ? XB : XF;
  const int ub = tid >> 6, uj = tid & 63;
  unsigned int* HXd = HX + dir * 6144;    // [slot:3][consumer:4][512]

  const float* bi = dir ? bih_b : bih_f;
  const float* bh = dir ? bhh_b : bhh_f;
  float bias0 = bi[0 * 256 + 64 * m + uj] + bh[0 * 256 + 64 * m + uj];
  float bias1 = bi[1 * 256 + 64 * m + uj] + bh[1 * 256 + 64 * m + uj];
  float bias2 = bi[2 * 256 + 64 * m + uj] + bh[2 * 256 + 64 * m + uj];
  float bias3 = bi[3 * 256 + 64 * m + uj] + bh[3 * 256 + 64 * m + uj];

  { // load weight slice (B-frag order, coalesced)
    const uint4* WT4 = (const uint4*)(WT + dir * 131072 + m * 32768);
    uint4* WL4 = (uint4*)WL;
    #pragma unroll
    for (int s = 0; s < 32; ++s)
      WL4[s * 256 + tid] = WT4[s * 256 + tid];
  }
  for (int i = tid; i < 2048; i += 256) H16[i] = 0;
  float c = 0.f;
  __syncthreads();

  const uint4* WL4 = (const uint4*)WL;
  const uint4* H16u4 = (const uint4*)H16;

  float4v acc[4];
  auto kchunk = [&](int kc){
    uint4 av = H16u4[(lane & 15) * 32 + kc * 4 + quad];
    short8 af = *(const short8*)&av;
    #pragma unroll
    for (int t = 0; t < 4; ++t){
      int nt = w * 4 + t;
      uint4 bv = WL4[(kc * 16 + nt) * 64 + lane];
      short8 bf = *(const short8*)&bv;
      acc[t] = __builtin_amdgcn_mfma_f32_16x16x32_bf16(af, bf, acc[t], 0, 0, 0);
    }
  };

  for (int t = 0; t < TT; ++t){
    const int tb = dir ? (TT - 1 - t) : t;
    const float* xr = Xp + (size_t)(tb * 4 + ub) * 1024 + 64 * m + uj;
    float x0 = xr[0], x1 = xr[256], x2 = xr[512], x3 = xr[768];

    #pragma unroll
    for (int i = 0; i < 4; ++i) acc[i] = (float4v){0,0,0,0};
    // Phase A: own k-range — peer-independent
    kchunk(2 * m); kchunk(2 * m + 1);
    // Phase B: fetch peer h slices, poll payload
    if (t > 0 && w > 0){
      int qp = (m + w) & 3;
      unsigned int* S = HXd + ((t - 1) % 3) * 2048 + m * 512;
      int b2 = lane >> 5, p2 = lane & 31;
      int i1 = b2 * 128 + 32 * qp + p2;
      int i2 = (b2 + 2) * 128 + 32 * qp + p2;
      unsigned int v1, v2;
      int guard = 0;
      while ((v1 = __hip_atomic_load(&S[i1], __ATOMIC_RELAXED, __HIP_MEMORY_SCOPE_AGENT)) == SENT
             && guard < 200000){ __builtin_amdgcn_s_sleep(1); ++guard; }
      guard = 0;
      while ((v2 = __hip_atomic_load(&S[i2], __ATOMIC_RELAXED, __HIP_MEMORY_SCOPE_AGENT)) == SENT
             && guard < 200000){ __builtin_amdgcn_s_sleep(1); ++guard; }
      H16[i1] = v1; H16[i2] = v2;
      __hip_atomic_store(&S[i1], SENT, __ATOMIC_RELAXED, __HIP_MEMORY_SCOPE_AGENT);
      __hip_atomic_store(&S[i2], SENT, __ATOMIC_RELAXED, __HIP_MEMORY_SCOPE_AGENT);
    }
    __syncthreads();
    // Phase C: remaining 6 k-chunks
    #pragma unroll
    for (int i = 1; i < 4; ++i){
      int qp = (m + i) & 3;
      kchunk(2 * qp); kchunk(2 * qp + 1);
    }
    // gate output: quad 0 holds rows 0-3 = batches
    if (quad == 0){
      #pragma unroll
      for (int tt = 0; tt < 4; ++tt){
        int l = (w * 4 + tt) * 16 + r;
        glds[0][l] = acc[tt][0];
        glds[1][l] = acc[tt][1];
        glds[2][l] = acc[tt][2];
        glds[3][l] = acc[tt][3];
      }
    }
    __syncthreads();

    float gi = glds[ub][uj]        + bias0 + x0;
    float gf = glds[ub][64 + uj]   + bias1 + x1;
    float gg = glds[ub][128 + uj]  + bias2 + x2;
    float go = glds[ub][192 + uj]  + bias3 + x3;
    float si = 1.f / (1.f + __expf(-gi));
    float sf = 1.f / (1.f + __expf(-gf));
    float so = 1.f / (1.f + __expf(-go));
    float tg = 1.f - 2.f / (1.f + __expf(2.f * gg));
    c = sf * c + si * tg;
    float ch = 1.f - 2.f / (1.f + __expf(2.f * c));
    float hval = so * ch;
    if (t == TT - 1){
      HT[(size_t)(dir * 4 + ub) * RHID + (64 * m + uj)] = hval;
      break;
    }
    unsigned int own = f2b(hval);
    unsigned int partner = ((unsigned int)__shfl_xor((int)own, 1)) & 0xffffu;
    unsigned int* S = HXd + (t % 3) * 2048;
    if ((uj & 1) == 0){
      unsigned int v = own | (partner << 16);
      int p = uj >> 1;
      int idx = ub * 128 + 32 * m + p;
      H16[idx] = v;
      #pragma unroll
      for (int cns = 1; cns < 4; ++cns)
        __hip_atomic_store(&S[((m + cns) & 3) * 512 + idx], v,
                           __ATOMIC_RELAXED, __HIP_MEMORY_SCOPE_AGENT);
    }
    __syncthreads();   // drains publish + clears before next step
  }
}

// ---------------- heads + Poincare projection, fp32 out ----------------
__global__ __launch_bounds__(512)
void head2_kernel(const float* __restrict__ HT,
                  const float* __restrict__ muW, const float* __restrict__ mub,
                  const float* __restrict__ lvW, const float* __restrict__ lvb,
                  float* __restrict__ out)
{
  __shared__ float feat[4][512];
  __shared__ float muv[4][64];
  __shared__ float lvv[4][64];
  int tid = threadIdx.x;
  for (int i = tid; i < 2048; i += 512){
    int rr = i >> 8, k = i & 255;
    int b = rr & 3, d = rr >> 2;
    feat[b][d * 256 + k] = HT[i];
  }
  __syncthreads();
  int w = tid >> 6, lane = tid & 63;
  for (int job = w; job < 512; job += 8){
    int j = job & 63, b = (job >> 6) & 3, mat = job >> 8;
    const float* W = (mat ? lvW : muW) + (size_t)j * 512;
    float s = 0.f;
    #pragma unroll
    for (int e = 0; e < 8; ++e) s += W[lane * 8 + e] * feat[b][lane * 8 + e];
    #pragma unroll
    for (int mm = 32; mm >= 1; mm >>= 1) s += __shfl_xor(s, mm);
    if (lane == 0){
      float v = s + (mat ? lvb[j] : mub[j]);
      if (mat) lvv[b][j] = v; else muv[b][j] = v;
    }
  }
  __syncthreads();
  if (tid < 256){
    int b = tid >> 6, j = tid & 63;
    float mu = muv[b][j];
    float sq = mu * mu;
    #pragma unroll
    for (int mm = 32; mm >= 1; mm >>= 1) sq += __shfl_xor(sq, mm);
    float nrm = sqrtf(sq);
    const float mxn = 1.0f - 4e-3f;
    if (nrm > mxn) mu = mu / nrm * mxn;
    out[b * 64 + j] = mu;
    out[256 + b * 64 + j] = lvv[b][j];
  }
}

extern "C" void kernel_launch(void* const* d_in, const int* in_sizes, int n_in,
                              void* d_out, int out_size, void* d_ws, size_t ws_size,
                              hipStream_t stream)
{
  const int* ei = (const int*)d_in[1];

  int*   ws_i    = (int*)d_ws;
  int*   dflag   = ws_i;
  float* FW   = (float*)d_ws;
  float* Wbuf = FW + FOFF_WBUF;
  int*   csr_row = (int*)(FW + FOFF_CSR);
  unsigned short* csr_src = (unsigned short*)(FW + FOFF_CSR + 132);
  float* XFp  = FW + FOFF_XFP;
  float* XBp  = FW + FOFF_XBP;
  float* HT   = FW + FOFF_HT;
  unsigned short* XSEQ = (unsigned short*)(FW + FOFF_XSEQ);
  unsigned short* PA   = (unsigned short*)(FW + FOFF_PA);
  unsigned short* PB   = (unsigned short*)(FW + FOFF_PB);
  unsigned short* Pb   = (unsigned short*)(FW + FOFF_P);
  unsigned int*   WT   = (unsigned int*)(FW + FOFF_WE);
  unsigned short* BBF  = (unsigned short*)(FW + FOFF_BBF);
  unsigned int*   HX   = (unsigned int*)(FW + FOFF_SYNC);

  // ---- dtype sniff + fused setup (+CSR +HX init) ----
  sniff_kernel<<<1, 256, 0, stream>>>((const unsigned short*)d_in[2], dflag);

  CvtArgs ca;
  static const int wsz[24] = {4096,256,256,256, 65536,256,256,256, 16384,64,64,64,
                              65536,262144,1024,1024, 65536,262144,1024,1024,
                              32768,64,32768,64};
  {
    int acc = 0;
    for (int k = 0; k < 24; ++k){ ca.src[k] = d_in[2 + k]; ca.off[k] = acc; acc += wsz[k]; }
    ca.off[24] = acc;
  }
  int nblk = (SP_TOTAL + 255) / 256 + 1;
  setup_kernel<<<nblk, 256, 0, stream>>>(ca, dflag, Wbuf, BBF, Pb, WT, HX,
                                         d_in[0], ei, csr_row, csr_src);

  // ---- GAT layers ----
  glayer_kernel<16><<<512, 256, 0, stream>>>(Pb, BBF + BOFF_G0, Wbuf,
                                             WOFF_G0AS, WOFF_G0AD, WOFF_G0B,
                                             csr_row, csr_src, PA);
  glayer_kernel<256><<<512, 256, 0, stream>>>(PA, BBF + BOFF_G1, Wbuf,
                                              WOFF_G1AS, WOFF_G1AD, WOFF_G1B,
                                              csr_row, csr_src, PB);
  glayer2_kernel<<<512, 256, 0, stream>>>(PB, BBF + BOFF_G2, Wbuf,
                                          csr_row, csr_src, XSEQ);

  // ---- LSTM input precompute ----
  mmx2_kernel<<<dim3(4, 16, 2), 256, 0, stream>>>(XSEQ, BBF + BOFF_WF, BBF + BOFF_WB,
                                                  XFp, XBp, 256, 1024, 64);

  // ---- LSTM: MFMA gates + sentinel sync (HX pre-set to SENT by setup) ----
  lstm13_kernel<<<8, 256, 0, stream>>>(XFp, XBp, WT,
                                       Wbuf + WOFF_BIHF, Wbuf + WOFF_BHHF,
                                       Wbuf + WOFF_BIHB, Wbuf + WOFF_BHHB,
                                       HX, HT);

  // ---- heads + projection ----
  head2_kernel<<<1, 512, 0, stream>>>(HT, Wbuf + WOFF_MUW, Wbuf + WOFF_MUB,
                                      Wbuf + WOFF_LVW, Wbuf + WOFF_LVB, (float*)d_out);
}

// Round 19
// 414.107 us; speedup vs baseline: 1.2551x; 1.0257x over previous
//
#include <hip/hip_runtime.h>
#include <hip/hip_bf16.h>

// ---- problem constants ----
#define BSZ 4
#define TT 64
#define NNODE 128
#define NFEAT 16
#define HIDD 64
#define NHEAD 4
#define RHID 256
#define LDIM 64
#define EPG 1024
#define NGRAPH (BSZ*TT)          // 256
#define NTOT (NGRAPH*NNODE)      // 32768
#define ESLOTS (EPG+NNODE)       // 1152

// ---- canonical fp32 weight buffer offsets (floats) ----
#define WOFF_G0W 0
#define WOFF_G0AS 4096
#define WOFF_G0AD 4352
#define WOFF_G0B 4608
#define WOFF_G1W 4864
#define WOFF_G1AS 70400
#define WOFF_G1AD 70656
#define WOFF_G1B 70912
#define WOFF_G2W 71168
#define WOFF_G2AS 87552
#define WOFF_G2AD 87616
#define WOFF_G2B 87680
#define WOFF_WIHF 87744
#define WOFF_WHHF 153280
#define WOFF_BIHF 415424
#define WOFF_BHHF 416448
#define WOFF_WIHB 417472
#define WOFF_WHHB 483008
#define WOFF_BIHB 745152
#define WOFF_BHHB 746176
#define WOFF_MUW 747200
#define WOFF_MUB 779968
#define WOFF_LVW 780032
#define WOFF_LVB 812800
#define WTOTAL   812864

// ---- workspace float offsets ----
#define FOFF_WBUF 4096
#define FOFF_CSR  1052672      // csr_row int[132], csr_src u16[1152], FL int[1024] @ +1024
#define FOFF_SYNC 1314816      // HX: 2*3*4*512 uints (sentinel protocol)
#define FOFF_WE   1576960      // WTB (bf16 B-frag Whh, 262144 uints)
#define FOFF_BBF  1900000      // bf16 B matrices (u16 view)
#define FOFF_XFP  2756608
#define FOFF_XBP  3018752
#define FOFF_HT   3280896
#define FOFF_XSEQ 3282944
#define FOFF_PA   3291136      // P0 [32768][256] bf16
#define FOFF_PB   5388288      // P1 [32768][256] bf16
#define FOFF_P    7485440      // X  [32768][16]  bf16

// bf16 B-matrix u16 offsets inside BBF (G0/G1/G2 stored TRANSPOSED [out][in])
#define BOFF_G0 0
#define BOFF_G1 4096
#define BOFF_G2 69632
#define BOFF_WF 86016
#define BOFF_WB 151552
#define BTOTAL  217088

// setup phases
#define SP_CVTX  (WTOTAL + BTOTAL)            // 1029952
#define SP_WHH   (SP_CVTX + NTOT*NFEAT)       // 1554240
#define SP_HX    (SP_WHH + 262144)            // 1816384
#define SP_FL    (SP_HX + 12288)              // 1828672
#define SP_TOTAL (SP_FL + 1024)               // 1829696

#define SENT 0xFFFFFFFFu

typedef __attribute__((ext_vector_type(8))) short short8;
typedef __attribute__((ext_vector_type(4))) float float4v;

__device__ __forceinline__ float b2f(unsigned short u){
  union { unsigned int i; float f; } v; v.i = ((unsigned int)u) << 16; return v.f;
}
__device__ __forceinline__ unsigned short f2b(float f){
  __hip_bfloat16 h = __float2bfloat16(f);
  union { __hip_bfloat16 h; unsigned short u; } v; v.h = h; return v.u;
}
__device__ __forceinline__ float ldf(const void* p, int i, int flag){
  return flag ? b2f(((const unsigned short*)p)[i]) : ((const float*)p)[i];
}
__device__ __forceinline__ float h2f(unsigned short s){
  union { _Float16 hh; unsigned short s; } u; u.s = s; return (float)u.hh;
}
__device__ __forceinline__ unsigned short f2h(float f){
  union { _Float16 hh; unsigned short s; } u; u.hh = (_Float16)f; return u.s;
}
// uniform dtype sniff: sample 32 fixed even-u16s of gat0_W (bf16 N(0,0.1) vs fp32 halves)
__device__ __forceinline__ int sniff32(const unsigned short* w){
  int ok = 0;
  #pragma unroll
  for (int i = 0; i < 32; ++i){
    float a = fabsf(b2f(w[2 * i]));
    if (a > 1e-8f && a < 4.f) ok++;
  }
  return ok >= 16 ? 1 : 0;
}

// ---------------- fused setup: sniff + cvtw + packb(T) + cvtx + packwhh + HX + FL + CSR ----------------
struct CvtArgs {
  const void* src[24];
  int off[25];
};
__global__ void setup_kernel(CvtArgs a,
                             float* __restrict__ W, unsigned short* __restrict__ BBF,
                             unsigned short* __restrict__ P, unsigned int* __restrict__ WT,
                             unsigned int* __restrict__ HX, int* __restrict__ FL,
                             const void* __restrict__ x, const int* __restrict__ ei,
                             int* __restrict__ csr_row, unsigned short* __restrict__ csr_src)
{
  __shared__ int cnt[NNODE];
  __shared__ int off[NNODE];
  __shared__ int wo[NNODE];
  const int tid = threadIdx.x;

  if (blockIdx.x == gridDim.x - 1){
    // ---- CSR build with parallel scan ----
    if (tid < NNODE) cnt[tid] = 0;
    __syncthreads();
    for (int i = tid; i < ESLOTS; i += 256){
      int d = (i < EPG) ? ei[EPG + i] : (i - EPG);
      atomicAdd(&cnt[d], 1);
    }
    __syncthreads();
    if (tid < NNODE) off[tid] = cnt[tid];
    for (int o = 1; o < NNODE; o <<= 1){
      __syncthreads();
      int t = (tid < NNODE && tid >= o) ? off[tid - o] : 0;
      __syncthreads();
      if (tid < NNODE) off[tid] += t;
    }
    __syncthreads();
    if (tid < NNODE){
      wo[tid] = off[tid] - cnt[tid];
      csr_row[tid + 1] = off[tid];
    }
    if (tid == 0) csr_row[0] = 0;
    __syncthreads();
    for (int i = tid; i < ESLOTS; i += 256){
      int s, d;
      if (i < EPG){ s = ei[i]; d = ei[EPG + i]; } else { s = i - EPG; d = i - EPG; }
      int pos = atomicAdd(&wo[d], 1);
      csr_src[pos] = (unsigned short)s;
    }
    return;
  }

  int id = blockIdx.x * blockDim.x + tid;
  if (id >= SP_TOTAL) return;
  int fl = sniff32((const unsigned short*)a.src[0]);
  if (id < WTOTAL){
    int k = 0;
    while (id >= a.off[k + 1]) ++k;
    W[id] = ldf(a.src[k], id - a.off[k], fl);
  } else if (id < WTOTAL + BTOTAL){
    int r = id - WTOTAL;
    float v;
    if (r < BOFF_G1){
      int o = r >> 4, k = r & 15;
      v = ldf(a.src[0], k * 256 + o, fl);
    } else if (r < BOFF_G2){
      int rr = r - BOFF_G1; int o = rr >> 8, k = rr & 255;
      v = ldf(a.src[4], k * 256 + o, fl);
    } else if (r < BOFF_WF){
      int rr = r - BOFF_G2; int o = rr >> 8, k = rr & 255;
      v = ldf(a.src[8], k * 64 + o, fl);
    } else if (r < BOFF_WB){
      int q = r - BOFF_WF; int k = q >> 10, n = q & 1023;
      v = ldf(a.src[12], n * 64 + k, fl);
    } else {
      int q = r - BOFF_WB; int k = q >> 10, n = q & 1023;
      v = ldf(a.src[16], n * 64 + k, fl);
    }
    BBF[r] = f2b(v);
  } else if (id < SP_CVTX + NTOT * NFEAT){
    int r = id - SP_CVTX;
    P[r] = fl ? ((const unsigned short*)x)[r] : f2b(((const float*)x)[r]);
  } else if (id < SP_HX){
    // Whh -> bf16 B-fragment layout: WT[dir][m][kc][nt][lane] uint4 (pairs)
    int r0 = id - SP_WHH;
    int c = r0 & 3;
    int lane = (r0 >> 2) & 63;
    int nt = (r0 >> 8) & 15;
    int kc = (r0 >> 12) & 7;
    int m = (r0 >> 15) & 3;
    int dir = r0 >> 17;
    int l = nt * 16 + (lane & 15);
    int u = (l >> 6) * 256 + 64 * m + (l & 63);
    int k0 = kc * 32 + ((lane >> 4) << 3) + 2 * c;
    const void* Wsrc = dir ? a.src[17] : a.src[13];
    unsigned short va = f2b(ldf(Wsrc, u * RHID + k0, fl));
    unsigned short vb = f2b(ldf(Wsrc, u * RHID + k0 + 1, fl));
    WT[r0] = (unsigned int)va | ((unsigned int)vb << 16);
  } else if (id < SP_FL){
    HX[id - SP_HX] = SENT;
  } else {
    FL[id - SP_FL] = 0;
  }
}

// ---------------- fused 3-layer GAT + pool: 512 blocks, partner-flag sync between layers ----------------
__global__ __launch_bounds__(256)
void gat3_kernel(const unsigned short* Pb, const unsigned short* BBF,
                 const float* Wbuf,
                 const int* csr_row, const unsigned short* csr_src,
                 unsigned short* PA, unsigned short* PB,
                 unsigned short* XSEQ, int* FL)
{
  __shared__ unsigned short HAs[128 * 136];    // 34.8 KB (L2 phase uses [128*72] prefix)
  __shared__ unsigned short Bst[128 * 40];     // 10.2 KB
  __shared__ unsigned char  AWs8[1152 * 2];    //  2.3 KB (L0/L1 u8 alpha)
  __shared__ unsigned short AWsh[1152];        //  2.3 KB (L2 f16 alpha)
  __shared__ unsigned short ALS16[256];
  __shared__ unsigned short ALD16[256];
  __shared__ float ALSf[128];
  __shared__ float ALDf[128];
  __shared__ int   rowL[132];
  __shared__ unsigned char srcL[1152];
  __shared__ float pools[8][32];

  const int tid = threadIdx.x;
  const int g = blockIdx.x >> 1, hb = blockIdx.x & 1;
  const int c0 = hb * 128;
  const int w = tid >> 6, lane = tid & 63, q = lane >> 4, r = lane & 15;

  for (int i = tid; i < 129; i += 256) rowL[i] = csr_row[i];
  for (int i = tid; i < 1152; i += 256) srcL[i] = (unsigned char)csr_src[i];
  __syncthreads();

  // ---- one 4-head half-layer: GEMM + attn + softmax(u8) + agg -> Pout (agent-relaxed) ----
  auto do_layer = [&](int KV, const unsigned short* Pin, const unsigned short* BT,
                      int asoff, int adoff, int boff, unsigned short* Pout){
    float4v acc0[8], acc1[8];
    #pragma unroll
    for (int i = 0; i < 8; ++i){ acc0[i] = (float4v){0,0,0,0}; acc1[i] = (float4v){0,0,0,0}; }
    const int KR = (KV + 31) / 32;
    for (int kr = 0; kr < KR; ++kr){
      const int kc = kr * 32;
      __syncthreads();
      {
        int n = tid >> 1, kb = (tid & 1) * 16;
        uint4 z = {0,0,0,0}; uint4 v0 = z, v1 = z;
        if (kb < KV)     v0 = *(const uint4*)(BT + (size_t)(c0 + n) * KV + kc + kb);
        if (kb + 8 < KV) v1 = *(const uint4*)(BT + (size_t)(c0 + n) * KV + kc + kb + 8);
        *(uint4*)&Bst[n * 40 + kb] = v0;
        *(uint4*)&Bst[n * 40 + kb + 8] = v1;
      }
      short8 a0 = {0,0,0,0,0,0,0,0}, a1 = {0,0,0,0,0,0,0,0};
      if (KV >= 32 || q < 2){
        a0 = *(const short8*)(Pin + (size_t)(g * 128 + 16 * w       + r) * KV + kc + q * 8);
        a1 = *(const short8*)(Pin + (size_t)(g * 128 + 16 * (w + 4) + r) * KV + kc + q * 8);
      }
      __syncthreads();
      #pragma unroll
      for (int nt = 0; nt < 8; ++nt){
        short8 bf = *(const short8*)&Bst[(16 * nt + r) * 40 + q * 8];
        acc0[nt] = __builtin_amdgcn_mfma_f32_16x16x32_bf16(a0, bf, acc0[nt], 0, 0, 0);
        acc1[nt] = __builtin_amdgcn_mfma_f32_16x16x32_bf16(a1, bf, acc1[nt], 0, 0, 0);
      }
    }
    __syncthreads();
    #pragma unroll
    for (int nt = 0; nt < 8; ++nt)
      #pragma unroll
      for (int i = 0; i < 4; ++i){
        HAs[(16 * w       + q * 4 + i) * 136 + 16 * nt + r] = f2b(acc0[nt][i]);
        HAs[(16 * (w + 4) + q * 4 + i) * 136 + 16 * nt + r] = f2b(acc1[nt][i]);
      }
    __syncthreads();

    {
      float as0 = Wbuf[asoff + c0 + 2 * lane], as1 = Wbuf[asoff + c0 + 2 * lane + 1];
      float ad0 = Wbuf[adoff + c0 + 2 * lane], ad1 = Wbuf[adoff + c0 + 2 * lane + 1];
      for (int it = 0; it < 32; ++it){
        int n = it * 4 + w;
        float e0 = b2f(HAs[n * 136 + 2 * lane]);
        float e1 = b2f(HAs[n * 136 + 2 * lane + 1]);
        float vs = e0 * as0 + e1 * as1;
        float vd = e0 * ad0 + e1 * ad1;
        #pragma unroll
        for (int m = 16; m >= 1; m >>= 1){ vs += __shfl_xor(vs, m); vd += __shfl_xor(vd, m); }
        if ((lane & 31) == 0){
          ALS16[n * 2 + (lane >> 5)] = f2h(vs);
          ALD16[n * 2 + (lane >> 5)] = f2h(vd);
        }
      }
    }
    __syncthreads();

    {
      int n = tid >> 1, hl = tid & 1;
      float aldv = h2f(ALD16[n * 2 + hl]);
      int rs = rowL[n], re = rowL[n + 1];
      float mx = -3e38f, den = 0.f;
      for (int j = rs; j < re; ++j){
        float v = h2f(ALS16[srcL[j] * 2 + hl]) + aldv;
        v = v > 0.f ? v : 0.2f * v;
        if (v > mx){ den = den * __expf(mx - v) + 1.f; mx = v; }
        else den += __expf(v - mx);
      }
      float iden = 1.f / (den + 1e-16f);
      for (int j = rs; j < re; ++j){
        float v = h2f(ALS16[srcL[j] * 2 + hl]) + aldv;
        v = v > 0.f ? v : 0.2f * v;
        float al = __expf(v - mx) * iden;
        AWs8[j * 2 + hl] = (unsigned char)(al * 255.f + 0.5f);
      }
    }
    __syncthreads();

    {
      int hl = lane >> 5;
      int fl2 = 2 * lane;
      float bz0 = Wbuf[boff + c0 + fl2], bz1 = Wbuf[boff + c0 + fl2 + 1];
      for (int n = w; n < 128; n += 4){
        int rs = rowL[n], re = rowL[n + 1];
        float A0 = 0.f, A1 = 0.f;
        for (int j = rs; j < re; j += 4){
          int cnt2 = re - j;
          int i1 = j + (cnt2 > 1 ? 1 : 0);
          int i2 = j + (cnt2 > 2 ? 2 : 0);
          int i3 = j + (cnt2 > 3 ? 3 : 0);
          int s0 = srcL[j], s1 = srcL[i1], s2 = srcL[i2], s3 = srcL[i3];
          float w0 = AWs8[j * 2 + hl] * (1.f / 255.f);
          float w1 = cnt2 > 1 ? AWs8[i1 * 2 + hl] * (1.f / 255.f) : 0.f;
          float w2 = cnt2 > 2 ? AWs8[i2 * 2 + hl] * (1.f / 255.f) : 0.f;
          float w3 = cnt2 > 3 ? AWs8[i3 * 2 + hl] * (1.f / 255.f) : 0.f;
          const unsigned short* p0 = &HAs[s0 * 136 + fl2];
          const unsigned short* p1 = &HAs[s1 * 136 + fl2];
          const unsigned short* p2 = &HAs[s2 * 136 + fl2];
          const unsigned short* p3 = &HAs[s3 * 136 + fl2];
          A0 += w0 * b2f(p0[0]) + w1 * b2f(p1[0]) + w2 * b2f(p2[0]) + w3 * b2f(p3[0]);
          A1 += w0 * b2f(p0[1]) + w1 * b2f(p1[1]) + w2 * b2f(p2[1]) + w3 * b2f(p3[1]);
        }
        A0 += bz0; A1 += bz1;
        unsigned short o0 = f2b(A0 > 0.f ? A0 : 0.f);
        unsigned short o1 = f2b(A1 > 0.f ? A1 : 0.f);
        unsigned int pk = (unsigned int)o0 | ((unsigned int)o1 << 16);
        __hip_atomic_store((unsigned int*)&Pout[(size_t)(g * 128 + n) * 256 + c0 + fl2], pk,
                           __ATOMIC_RELAXED, __HIP_MEMORY_SCOPE_AGENT);
      }
    }
  };

  // ---- partner sync: own half published -> wait partner's half ----
  auto sync_partner = [&](int* FLx){
    __syncthreads();                 // drains payload stores (vmcnt) before release
    if (tid == 0){
      __hip_atomic_store(&FLx[blockIdx.x], 1, __ATOMIC_RELEASE, __HIP_MEMORY_SCOPE_AGENT);
      int guard = 0;
      while (__hip_atomic_load(&FLx[blockIdx.x ^ 1], __ATOMIC_ACQUIRE,
                               __HIP_MEMORY_SCOPE_AGENT) == 0 && guard < 200000){
        __builtin_amdgcn_s_sleep(1);
        ++guard;
      }
    }
    __syncthreads();
  };

  //======== Layer 0 / Layer 1 ========
  do_layer(16, Pb, BBF + BOFF_G0, WOFF_G0AS, WOFF_G0AD, WOFF_G0B, PA);
  sync_partner(FL);
  do_layer(256, PA, BBF + BOFF_G1, WOFF_G1AS, WOFF_G1AD, WOFF_G1B, PB);
  sync_partner(FL + 512);

  //======== Layer 2 (1 head, HD=64, duplicated GEMM, split agg/pool by half) ========
  {
    const unsigned short* BT = BBF + BOFF_G2;
    float4v acc0[4], acc1[4];
    #pragma unroll
    for (int i = 0; i < 4; ++i){ acc0[i] = (float4v){0,0,0,0}; acc1[i] = (float4v){0,0,0,0}; }
    for (int kr = 0; kr < 8; ++kr){
      const int kc = kr * 32;
      __syncthreads();
      {
        int n = tid >> 2, kb = (tid & 3) * 8;
        uint4 v = *(const uint4*)(BT + (size_t)n * 256 + kc + kb);
        *(uint4*)&Bst[n * 40 + kb] = v;
      }
      short8 a0 = *(const short8*)(PB + (size_t)(g * 128 + 16 * w       + r) * 256 + kc + q * 8);
      short8 a1 = *(const short8*)(PB + (size_t)(g * 128 + 16 * (w + 4) + r) * 256 + kc + q * 8);
      __syncthreads();
      #pragma unroll
      for (int nt = 0; nt < 4; ++nt){
        short8 bf = *(const short8*)&Bst[(16 * nt + r) * 40 + q * 8];
        acc0[nt] = __builtin_amdgcn_mfma_f32_16x16x32_bf16(a0, bf, acc0[nt], 0, 0, 0);
        acc1[nt] = __builtin_amdgcn_mfma_f32_16x16x32_bf16(a1, bf, acc1[nt], 0, 0, 0);
      }
    }
    __syncthreads();
    #pragma unroll
    for (int nt = 0; nt < 4; ++nt)
      #pragma unroll
      for (int i = 0; i < 4; ++i){
        HAs[(16 * w       + q * 4 + i) * 72 + 16 * nt + r] = f2b(acc0[nt][i]);
        HAs[(16 * (w + 4) + q * 4 + i) * 72 + 16 * nt + r] = f2b(acc1[nt][i]);
      }
    __syncthreads();

    {
      float asv = Wbuf[WOFF_G2AS + lane];
      float adv = Wbuf[WOFF_G2AD + lane];
      for (int it = 0; it < 32; ++it){
        int n = it * 4 + w;
        float e0 = b2f(HAs[n * 72 + lane]);
        float vs = e0 * asv, vd = e0 * adv;
        #pragma unroll
        for (int m = 32; m >= 1; m >>= 1){ vs += __shfl_xor(vs, m); vd += __shfl_xor(vd, m); }
        if (lane == 0){ ALSf[n] = vs; ALDf[n] = vd; }
      }
    }
    __syncthreads();
    if (tid < 128){
      int n = tid;
      float aldv = ALDf[n];
      int rs = rowL[n], re = rowL[n + 1];
      float mx = -3e38f, den = 0.f;
      for (int j = rs; j < re; ++j){
        float v = ALSf[srcL[j]] + aldv;
        v = v > 0.f ? v : 0.2f * v;
        if (v > mx){ den = den * __expf(mx - v) + 1.f; mx = v; }
        else den += __expf(v - mx);
      }
      float iden = 1.f / (den + 1e-16f);
      for (int j = rs; j < re; ++j){
        float v = ALSf[srcL[j]] + aldv;
        v = v > 0.f ? v : 0.2f * v;
        AWsh[j] = f2h(__expf(v - mx) * iden);
      }
    }
    __syncthreads();

    {
      int fl2 = lane & 31;
      int ng = lane >> 5;
      int col = hb * 32 + fl2;
      float bz = Wbuf[WOFF_G2B + col];
      float psum = 0.f;
      for (int n = w * 2 + ng; n < 128; n += 8){
        int rs = rowL[n], re = rowL[n + 1];
        float A0 = 0.f;
        for (int j = rs; j < re; j += 4){
          int cnt2 = re - j;
          int i1 = j + (cnt2 > 1 ? 1 : 0);
          int i2 = j + (cnt2 > 2 ? 2 : 0);
          int i3 = j + (cnt2 > 3 ? 3 : 0);
          int s0 = srcL[j], s1 = srcL[i1], s2 = srcL[i2], s3 = srcL[i3];
          float w0 = h2f(AWsh[j]);
          float w1 = cnt2 > 1 ? h2f(AWsh[i1]) : 0.f;
          float w2 = cnt2 > 2 ? h2f(AWsh[i2]) : 0.f;
          float w3 = cnt2 > 3 ? h2f(AWsh[i3]) : 0.f;
          A0 += w0 * b2f(HAs[s0 * 72 + col]) + w1 * b2f(HAs[s1 * 72 + col])
              + w2 * b2f(HAs[s2 * 72 + col]) + w3 * b2f(HAs[s3 * 72 + col]);
        }
        A0 += bz;
        psum += (A0 > 0.f ? A0 : 0.f);
      }
      pools[w * 2 + ng][fl2] = psum;
    }
    __syncthreads();
    if (tid < 32){
      float s = 0.f;
      #pragma unroll
      for (int p = 0; p < 8; ++p) s += pools[p][tid];
      int b = g >> 6, tq = g & 63;
      XSEQ[(size_t)(tq * BSZ + b) * HIDD + hb * 32 + tid] = f2b(s);
    }
  }
}

// ---------------- MFMA matmul for BOTH Wih GEMMs in one launch (z = dir) ----------------
__global__ __launch_bounds__(256)
void mmx2_kernel(const unsigned short* __restrict__ A,
                 const unsigned short* __restrict__ B0, const unsigned short* __restrict__ B1,
                 float* __restrict__ C0, float* __restrict__ C1, int M, int Nc, int K)
{
  __shared__ unsigned short As[64][40];
  __shared__ unsigned short Bs[64][40];
  const unsigned short* Bb = blockIdx.z ? B1 : B0;
  float* C = blockIdx.z ? C1 : C0;
  const int tid = threadIdx.x;
  const int w = tid >> 6, lane = tid & 63, q = lane >> 4, r = lane & 15;
  const int m0 = blockIdx.x * 64, n0 = blockIdx.y * 64;
  float4v acc0 = {0,0,0,0}, acc1 = {0,0,0,0}, acc2 = {0,0,0,0}, acc3 = {0,0,0,0};
  const int arow = tid >> 2, akb = (tid & 3) * 8;
  const int bk = tid >> 3, bnb = (tid & 7) * 8;
  for (int kc = 0; kc < K; kc += 32){
    int kw = K - kc; if (kw > 32) kw = 32;
    if (akb < kw){
      uint4 v = *(const uint4*)(A + (size_t)(m0 + arow) * K + kc + akb);
      *(uint4*)&As[arow][akb] = v;
    } else {
      uint4 z = {0,0,0,0}; *(uint4*)&As[arow][akb] = z;
    }
    if (bk < kw){
      uint4 v = *(const uint4*)(Bb + (size_t)(kc + bk) * Nc + n0 + bnb);
      const unsigned short* vs = (const unsigned short*)&v;
      #pragma unroll
      for (int e = 0; e < 8; ++e) Bs[bnb + e][bk] = vs[e];
    } else {
      #pragma unroll
      for (int e = 0; e < 8; ++e) Bs[bnb + e][bk] = 0;
    }
    __syncthreads();
    short8 af = *(const short8*)&As[16 * w + r][q * 8];
    short8 b0 = *(const short8*)&Bs[r][q * 8];
    short8 b1 = *(const short8*)&Bs[16 + r][q * 8];
    short8 b2 = *(const short8*)&Bs[32 + r][q * 8];
    short8 b3 = *(const short8*)&Bs[48 + r][q * 8];
    acc0 = __builtin_amdgcn_mfma_f32_16x16x32_bf16(af, b0, acc0, 0, 0, 0);
    acc1 = __builtin_amdgcn_mfma_f32_16x16x32_bf16(af, b1, acc1, 0, 0, 0);
    acc2 = __builtin_amdgcn_mfma_f32_16x16x32_bf16(af, b2, acc2, 0, 0, 0);
    acc3 = __builtin_amdgcn_mfma_f32_16x16x32_bf16(af, b3, acc3, 0, 0, 0);
    __syncthreads();
  }
  const int row = m0 + 16 * w + q * 4, col0 = n0 + r;
  #pragma unroll
  for (int i = 0; i < 4; ++i){
    size_t base = (size_t)(row + i) * Nc;
    C[base + col0]      = acc0[i];
    C[base + col0 + 16] = acc1[i];
    C[base + col0 + 32] = acc2[i];
    C[base + col0 + 48] = acc3[i];
  }
}

// ---------------- LSTM via MFMA: 8 WGs, sentinel sync; H16 rows padded (132 uints) ----------------
__global__ __launch_bounds__(256)
void lstm13_kernel(const float* __restrict__ XF, const float* __restrict__ XB,
                   const unsigned int* __restrict__ WT,
                   const float* __restrict__ bih_f, const float* __restrict__ bhh_f,
                   const float* __restrict__ bih_b, const float* __restrict__ bhh_b,
                   unsigned int* __restrict__ HX,
                   float* __restrict__ HT)
{
  __shared__ unsigned int WL[32768];      // 128 KB: [kc][nt][lane] uint4 flat
  __shared__ unsigned int H16[16 * 132];  // 8.25 KB: padded rows (33 uint4) kill 16-way conflicts
  __shared__ float glds[4][256];

  const int tid = threadIdx.x;
  const int m = blockIdx.x & 3, dir = blockIdx.x >> 2;
  const int w = tid >> 6, lane = tid & 63, quad = lane >> 4, r = lane & 15;
  const float* Xp = dir ? XB : XF;
  const int ub = tid >> 6, uj = tid & 63;
  unsigned int* HXd = HX + dir * 6144;    // [slot:3][consumer:4][512] (unpadded global layout)

  const float* bi = dir ? bih_b : bih_f;
  const float* bh = dir ? bhh_b : bhh_f;
  float bias0 = bi[0 * 256 + 64 * m + uj] + bh[0 * 256 + 64 * m + uj];
  float bias1 = bi[1 * 256 + 64 * m + uj] + bh[1 * 256 + 64 * m + uj];
  float bias2 = bi[2 * 256 + 64 * m + uj] + bh[2 * 256 + 64 * m + uj];
  float bias3 = bi[3 * 256 + 64 * m + uj] + bh[3 * 256 + 64 * m + uj];

  {
    const uint4* WT4 = (const uint4*)(WT + dir * 131072 + m * 32768);
    uint4* WL4 = (uint4*)WL;
    #pragma unroll
    for (int s = 0; s < 32; ++s)
      WL4[s * 256 + tid] = WT4[s * 256 + tid];
  }
  for (int i = tid; i < 16 * 132; i += 256) H16[i] = 0;
  float c = 0.f;
  __syncthreads();

  const uint4* WL4 = (const uint4*)WL;
  const uint4* H16u4 = (const uint4*)H16;

  float4v acc[4];
  auto kchunk = [&](int kc){
    uint4 av = H16u4[(lane & 15) * 33 + kc * 4 + quad];
    short8 af = *(const short8*)&av;
    #pragma unroll
    for (int t = 0; t < 4; ++t){
      int nt = w * 4 + t;
      uint4 bv = WL4[(kc * 16 + nt) * 64 + lane];
      short8 bf = *(const short8*)&bv;
      acc[t] = __builtin_amdgcn_mfma_f32_16x16x32_bf16(af, bf, acc[t], 0, 0, 0);
    }
  };

  for (int t = 0; t < TT; ++t){
    const int tb = dir ? (TT - 1 - t) : t;
    const float* xr = Xp + (size_t)(tb * 4 + ub) * 1024 + 64 * m + uj;
    float x0 = xr[0], x1 = xr[256], x2 = xr[512], x3 = xr[768];

    #pragma unroll
    for (int i = 0; i < 4; ++i) acc[i] = (float4v){0,0,0,0};
    kchunk(2 * m); kchunk(2 * m + 1);
    if (t > 0 && w > 0){
      int qp = (m + w) & 3;
      unsigned int* S = HXd + ((t - 1) % 3) * 2048 + m * 512;
      int b2 = lane >> 5, p2 = lane & 31;
      int i1G = b2 * 128 + 32 * qp + p2;
      int i2G = (b2 + 2) * 128 + 32 * qp + p2;
      int i1L = b2 * 132 + 32 * qp + p2;
      int i2L = (b2 + 2) * 132 + 32 * qp + p2;
      unsigned int v1, v2;
      int guard = 0;
      while ((v1 = __hip_atomic_load(&S[i1G], __ATOMIC_RELAXED, __HIP_MEMORY_SCOPE_AGENT)) == SENT
             && guard < 200000){ __builtin_amdgcn_s_sleep(1); ++guard; }
      guard = 0;
      while ((v2 = __hip_atomic_load(&S[i2G], __ATOMIC_RELAXED, __HIP_MEMORY_SCOPE_AGENT)) == SENT
             && guard < 200000){ __builtin_amdgcn_s_sleep(1); ++guard; }
      H16[i1L] = v1; H16[i2L] = v2;
      __hip_atomic_store(&S[i1G], SENT, __ATOMIC_RELAXED, __HIP_MEMORY_SCOPE_AGENT);
      __hip_atomic_store(&S[i2G], SENT, __ATOMIC_RELAXED, __HIP_MEMORY_SCOPE_AGENT);
    }
    __syncthreads();
    #pragma unroll
    for (int i = 1; i < 4; ++i){
      int qp = (m + i) & 3;
      kchunk(2 * qp); kchunk(2 * qp + 1);
    }
    if (quad == 0){
      #pragma unroll
      for (int tt = 0; tt < 4; ++tt){
        int l = (w * 4 + tt) * 16 + r;
        glds[0][l] = acc[tt][0];
        glds[1][l] = acc[tt][1];
        glds[2][l] = acc[tt][2];
        glds[3][l] = acc[tt][3];
      }
    }
    __syncthreads();

    float gi = glds[ub][uj]        + bias0 + x0;
    float gf = glds[ub][64 + uj]   + bias1 + x1;
    float gg = glds[ub][128 + uj]  + bias2 + x2;
    float go = glds[ub][192 + uj]  + bias3 + x3;
    float si = 1.f / (1.f + __expf(-gi));
    float sf = 1.f / (1.f + __expf(-gf));
    float so = 1.f / (1.f + __expf(-go));
    float tg = 1.f - 2.f / (1.f + __expf(2.f * gg));
    c = sf * c + si * tg;
    float ch = 1.f - 2.f / (1.f + __expf(2.f * c));
    float hval = so * ch;
    if (t == TT - 1){
      HT[(size_t)(dir * 4 + ub) * RHID + (64 * m + uj)] = hval;
      break;
    }
    unsigned int own = f2b(hval);
    unsigned int partner = ((unsigned int)__shfl_xor((int)own, 1)) & 0xffffu;
    unsigned int* S = HXd + (t % 3) * 2048;
    if ((uj & 1) == 0){
      unsigned int v = own | (partner << 16);
      int p = uj >> 1;
      int idxG = ub * 128 + 32 * m + p;
      int idxL = ub * 132 + 32 * m + p;
      H16[idxL] = v;
      #pragma unroll
      for (int cns = 1; cns < 4; ++cns)
        __hip_atomic_store(&S[((m + cns) & 3) * 512 + idxG], v,
                           __ATOMIC_RELAXED, __HIP_MEMORY_SCOPE_AGENT);
    }
    __syncthreads();
  }
}

// ---------------- heads + Poincare projection, fp32 out ----------------
__global__ __launch_bounds__(512)
void head2_kernel(const float* __restrict__ HT,
                  const float* __restrict__ muW, const float* __restrict__ mub,
                  const float* __restrict__ lvW, const float* __restrict__ lvb,
                  float* __restrict__ out)
{
  __shared__ float feat[4][512];
  __shared__ float muv[4][64];
  __shared__ float lvv[4][64];
  int tid = threadIdx.x;
  for (int i = tid; i < 2048; i += 512){
    int rr = i >> 8, k = i & 255;
    int b = rr & 3, d = rr >> 2;
    feat[b][d * 256 + k] = HT[i];
  }
  __syncthreads();
  int w = tid >> 6, lane = tid & 63;
  for (int job = w; job < 512; job += 8){
    int j = job & 63, b = (job >> 6) & 3, mat = job >> 8;
    const float* W = (mat ? lvW : muW) + (size_t)j * 512;
    float s = 0.f;
    #pragma unroll
    for (int e = 0; e < 8; ++e) s += W[lane * 8 + e] * feat[b][lane * 8 + e];
    #pragma unroll
    for (int mm = 32; mm >= 1; mm >>= 1) s += __shfl_xor(s, mm);
    if (lane == 0){
      float v = s + (mat ? lvb[j] : mub[j]);
      if (mat) lvv[b][j] = v; else muv[b][j] = v;
    }
  }
  __syncthreads();
  if (tid < 256){
    int b = tid >> 6, j = tid & 63;
    float mu = muv[b][j];
    float sq = mu * mu;
    #pragma unroll
    for (int mm = 32; mm >= 1; mm >>= 1) sq += __shfl_xor(sq, mm);
    float nrm = sqrtf(sq);
    const float mxn = 1.0f - 4e-3f;
    if (nrm > mxn) mu = mu / nrm * mxn;
    out[b * 64 + j] = mu;
    out[256 + b * 64 + j] = lvv[b][j];
  }
}

extern "C" void kernel_launch(void* const* d_in, const int* in_sizes, int n_in,
                              void* d_out, int out_size, void* d_ws, size_t ws_size,
                              hipStream_t stream)
{
  const int* ei = (const int*)d_in[1];

  float* FW   = (float*)d_ws;
  float* Wbuf = FW + FOFF_WBUF;
  int*   csr_row = (int*)(FW + FOFF_CSR);
  unsigned short* csr_src = (unsigned short*)(FW + FOFF_CSR + 132);
  int*   FL   = (int*)(FW + FOFF_CSR + 1024);     // FL1[512] + FL2[512]
  float* XFp  = FW + FOFF_XFP;
  float* XBp  = FW + FOFF_XBP;
  float* HT   = FW + FOFF_HT;
  unsigned short* XSEQ = (unsigned short*)(FW + FOFF_XSEQ);
  unsigned short* PA   = (unsigned short*)(FW + FOFF_PA);
  unsigned short* PB   = (unsigned short*)(FW + FOFF_PB);
  unsigned short* Pb   = (unsigned short*)(FW + FOFF_P);
  unsigned int*   WT   = (unsigned int*)(FW + FOFF_WE);
  unsigned short* BBF  = (unsigned short*)(FW + FOFF_BBF);
  unsigned int*   HX   = (unsigned int*)(FW + FOFF_SYNC);

  // ---- fused setup (sniff inline, +CSR +HX +FL init) ----
  CvtArgs ca;
  static const int wsz[24] = {4096,256,256,256, 65536,256,256,256, 16384,64,64,64,
                              65536,262144,1024,1024, 65536,262144,1024,1024,
                              32768,64,32768,64};
  {
    int acc = 0;
    for (int k = 0; k < 24; ++k){ ca.src[k] = d_in[2 + k]; ca.off[k] = acc; acc += wsz[k]; }
    ca.off[24] = acc;
  }
  int nblk = (SP_TOTAL + 255) / 256 + 1;
  setup_kernel<<<nblk, 256, 0, stream>>>(ca, Wbuf, BBF, Pb, WT, HX, FL,
                                         d_in[0], ei, csr_row, csr_src);

  // ---- fused 3-layer GAT + pool: 512 blocks, partner-flag sync between layers ----
  gat3_kernel<<<512, 256, 0, stream>>>(Pb, BBF, Wbuf, csr_row, csr_src, PA, PB, XSEQ, FL);

  // ---- LSTM input precompute ----
  mmx2_kernel<<<dim3(4, 16, 2), 256, 0, stream>>>(XSEQ, BBF + BOFF_WF, BBF + BOFF_WB,
                                                  XFp, XBp, 256, 1024, 64);

  // ---- LSTM: MFMA gates + sentinel sync ----
  lstm13_kernel<<<8, 256, 0, stream>>>(XFp, XBp, WT,
                                       Wbuf + WOFF_BIHF, Wbuf + WOFF_BHHF,
                                       Wbuf + WOFF_BIHB, Wbuf + WOFF_BHHB,
                                       HX, HT);

  // ---- heads + projection ----
  head2_kernel<<<1, 512, 0, stream>>>(HT, Wbuf + WOFF_MUW, Wbuf + WOFF_MUB,
                                      Wbuf + WOFF_LVW, Wbuf + WOFF_LVB, (float*)d_out);
}

// Round 20
// 385.506 us; speedup vs baseline: 1.3482x; 1.0742x over previous
//
#include <hip/hip_runtime.h>
#include <hip/hip_bf16.h>

// ---- problem constants ----
#define BSZ 4
#define TT 64
#define NNODE 128
#define NFEAT 16
#define HIDD 64
#define NHEAD 4
#define RHID 256
#define LDIM 64
#define EPG 1024
#define NGRAPH (BSZ*TT)          // 256
#define NTOT (NGRAPH*NNODE)      // 32768
#define ESLOTS (EPG+NNODE)       // 1152

// ---- canonical fp32 weight buffer offsets (floats) ----
#define WOFF_G0W 0
#define WOFF_G0AS 4096
#define WOFF_G0AD 4352
#define WOFF_G0B 4608
#define WOFF_G1W 4864
#define WOFF_G1AS 70400
#define WOFF_G1AD 70656
#define WOFF_G1B 70912
#define WOFF_G2W 71168
#define WOFF_G2AS 87552
#define WOFF_G2AD 87616
#define WOFF_G2B 87680
#define WOFF_WIHF 87744
#define WOFF_WHHF 153280
#define WOFF_BIHF 415424
#define WOFF_BHHF 416448
#define WOFF_WIHB 417472
#define WOFF_WHHB 483008
#define WOFF_BIHB 745152
#define WOFF_BHHB 746176
#define WOFF_MUW 747200
#define WOFF_MUB 779968
#define WOFF_LVW 780032
#define WOFF_LVB 812800
#define WTOTAL   812864

// ---- workspace float offsets ----
#define FOFF_WBUF 4096
#define FOFF_CSR  1052672      // csr_row int[132], csr_src u16[1152], FL int[1024] @ +1024
#define FOFF_SYNC 1314816      // HX: 2*3*4*512 uints (sentinel protocol)
#define FOFF_WE   1576960      // WTB (bf16 B-frag Whh, 262144 uints)
#define FOFF_BBF  1900000      // bf16 B matrices (u16 view)
#define FOFF_XFP  2756608
#define FOFF_XBP  3018752
#define FOFF_HT   3280896
#define FOFF_XSEQ 3282944
#define FOFF_PA   3291136      // P0 [32768][256] bf16
#define FOFF_PB   5388288      // P1 [32768][256] bf16
#define FOFF_P    7485440      // X  [32768][16]  bf16

// bf16 B-matrix u16 offsets inside BBF (G0/G1/G2 stored TRANSPOSED [out][in])
#define BOFF_G0 0
#define BOFF_G1 4096
#define BOFF_G2 69632
#define BOFF_WF 86016
#define BOFF_WB 151552
#define BTOTAL  217088

// setup phases
#define SP_CVTX  (WTOTAL + BTOTAL)            // 1029952
#define SP_WHH   (SP_CVTX + NTOT*NFEAT)       // 1554240
#define SP_HX    (SP_WHH + 262144)            // 1816384
#define SP_FL    (SP_HX + 12288)              // 1828672
#define SP_TOTAL (SP_FL + 1024)               // 1829696

#define SENT 0xFFFFFFFFu

typedef __attribute__((ext_vector_type(8))) short short8;
typedef __attribute__((ext_vector_type(4))) float float4v;

__device__ __forceinline__ float b2f(unsigned short u){
  union { unsigned int i; float f; } v; v.i = ((unsigned int)u) << 16; return v.f;
}
__device__ __forceinline__ unsigned short f2b(float f){
  __hip_bfloat16 h = __float2bfloat16(f);
  union { __hip_bfloat16 h; unsigned short u; } v; v.h = h; return v.u;
}
__device__ __forceinline__ float ldf(const void* p, int i, int flag){
  return flag ? b2f(((const unsigned short*)p)[i]) : ((const float*)p)[i];
}
__device__ __forceinline__ float h2f(unsigned short s){
  union { _Float16 hh; unsigned short s; } u; u.s = s; return (float)u.hh;
}
__device__ __forceinline__ unsigned short f2h(float f){
  union { _Float16 hh; unsigned short s; } u; u.hh = (_Float16)f; return u.s;
}
// uniform dtype sniff: sample 32 fixed even-u16s of gat0_W
__device__ __forceinline__ int sniff32(const unsigned short* w){
  int ok = 0;
  #pragma unroll
  for (int i = 0; i < 32; ++i){
    float a = fabsf(b2f(w[2 * i]));
    if (a > 1e-8f && a < 4.f) ok++;
  }
  return ok >= 16 ? 1 : 0;
}

// ---------------- fused setup: sniff + cvtw + packb(T) + cvtx + packwhh + HX + FL + CSR ----------------
struct CvtArgs {
  const void* src[24];
  int off[25];
};
__global__ void setup_kernel(CvtArgs a,
                             float* __restrict__ W, unsigned short* __restrict__ BBF,
                             unsigned short* __restrict__ P, unsigned int* __restrict__ WT,
                             unsigned int* __restrict__ HX, int* __restrict__ FL,
                             const void* __restrict__ x, const int* __restrict__ ei,
                             int* __restrict__ csr_row, unsigned short* __restrict__ csr_src)
{
  __shared__ int cnt[NNODE];
  __shared__ int off[NNODE];
  __shared__ int wo[NNODE];
  const int tid = threadIdx.x;

  if (blockIdx.x == gridDim.x - 1){
    if (tid < NNODE) cnt[tid] = 0;
    __syncthreads();
    for (int i = tid; i < ESLOTS; i += 256){
      int d = (i < EPG) ? ei[EPG + i] : (i - EPG);
      atomicAdd(&cnt[d], 1);
    }
    __syncthreads();
    if (tid < NNODE) off[tid] = cnt[tid];
    for (int o = 1; o < NNODE; o <<= 1){
      __syncthreads();
      int t = (tid < NNODE && tid >= o) ? off[tid - o] : 0;
      __syncthreads();
      if (tid < NNODE) off[tid] += t;
    }
    __syncthreads();
    if (tid < NNODE){
      wo[tid] = off[tid] - cnt[tid];
      csr_row[tid + 1] = off[tid];
    }
    if (tid == 0) csr_row[0] = 0;
    __syncthreads();
    for (int i = tid; i < ESLOTS; i += 256){
      int s, d;
      if (i < EPG){ s = ei[i]; d = ei[EPG + i]; } else { s = i - EPG; d = i - EPG; }
      int pos = atomicAdd(&wo[d], 1);
      csr_src[pos] = (unsigned short)s;
    }
    return;
  }

  int id = blockIdx.x * blockDim.x + tid;
  if (id >= SP_TOTAL) return;
  int fl = sniff32((const unsigned short*)a.src[0]);
  if (id < WTOTAL){
    int k = 0;
    while (id >= a.off[k + 1]) ++k;
    W[id] = ldf(a.src[k], id - a.off[k], fl);
  } else if (id < WTOTAL + BTOTAL){
    int r = id - WTOTAL;
    float v;
    if (r < BOFF_G1){
      int o = r >> 4, k = r & 15;
      v = ldf(a.src[0], k * 256 + o, fl);
    } else if (r < BOFF_G2){
      int rr = r - BOFF_G1; int o = rr >> 8, k = rr & 255;
      v = ldf(a.src[4], k * 256 + o, fl);
    } else if (r < BOFF_WF){
      int rr = r - BOFF_G2; int o = rr >> 8, k = rr & 255;
      v = ldf(a.src[8], k * 64 + o, fl);
    } else if (r < BOFF_WB){
      int q = r - BOFF_WF; int k = q >> 10, n = q & 1023;
      v = ldf(a.src[12], n * 64 + k, fl);
    } else {
      int q = r - BOFF_WB; int k = q >> 10, n = q & 1023;
      v = ldf(a.src[16], n * 64 + k, fl);
    }
    BBF[r] = f2b(v);
  } else if (id < SP_CVTX + NTOT * NFEAT){
    int r = id - SP_CVTX;
    P[r] = fl ? ((const unsigned short*)x)[r] : f2b(((const float*)x)[r]);
  } else if (id < SP_HX){
    int r0 = id - SP_WHH;
    int c = r0 & 3;
    int lane = (r0 >> 2) & 63;
    int nt = (r0 >> 8) & 15;
    int kc = (r0 >> 12) & 7;
    int m = (r0 >> 15) & 3;
    int dir = r0 >> 17;
    int l = nt * 16 + (lane & 15);
    int u = (l >> 6) * 256 + 64 * m + (l & 63);
    int k0 = kc * 32 + ((lane >> 4) << 3) + 2 * c;
    const void* Wsrc = dir ? a.src[17] : a.src[13];
    unsigned short va = f2b(ldf(Wsrc, u * RHID + k0, fl));
    unsigned short vb = f2b(ldf(Wsrc, u * RHID + k0 + 1, fl));
    WT[r0] = (unsigned int)va | ((unsigned int)vb << 16);
  } else if (id < SP_FL){
    HX[id - SP_HX] = SENT;
  } else {
    FL[id - SP_FL] = 0;
  }
}

// ---------------- fused 3-layer GAT + pool: 512 blocks, MFMA aggregation ----------------
// HT_ holds h TRANSPOSED [col][node]; AD is a union: B-staging during GEMM, dense-alpha
// [dst][src] (bf16) during aggregation. Agg = alpha @ H via MFMA (was scalar edge loops).
__global__ __launch_bounds__(256)
void gat3_kernel(const unsigned short* Pb, const unsigned short* BBF,
                 const float* Wbuf,
                 const int* csr_row, const unsigned short* csr_src,
                 unsigned short* PA, unsigned short* PB,
                 unsigned short* XSEQ, int* FL)
{
  __shared__ unsigned short HT_[128 * 136];   // 34.8 KB  h^T [col][node]
  __shared__ unsigned short AD[128 * 136];    // 34.8 KB  union: Bst / alpha-dense
  __shared__ unsigned short ALS16[256];
  __shared__ unsigned short ALD16[256];
  __shared__ float ALSf[128];
  __shared__ float ALDf[128];
  __shared__ int   rowL[132];
  __shared__ unsigned char srcL[1152];
  __shared__ float pools[4][64];

  const int tid = threadIdx.x;
  const int g = blockIdx.x >> 1, hb = blockIdx.x & 1;
  const int c0 = hb * 128;
  const int w = tid >> 6, lane = tid & 63, q = lane >> 4, r = lane & 15;
  unsigned short* Bst = AD;

  for (int i = tid; i < 129; i += 256) rowL[i] = csr_row[i];
  for (int i = tid; i < 1152; i += 256) srcL[i] = (unsigned char)csr_src[i];
  __syncthreads();

  // ---- GEMM producing h^T in HT_: NT n-tiles (8 => 128 cols at c0; 4 => 64 cols at 0) ----
  auto gemm_T = [&](int KV, int NT, const unsigned short* Pin, const unsigned short* BT){
    float4v acc0[8], acc1[8];
    #pragma unroll
    for (int i = 0; i < 8; ++i){ acc0[i] = (float4v){0,0,0,0}; acc1[i] = (float4v){0,0,0,0}; }
    const int cbase = (NT == 8) ? c0 : 0;
    const int KR = (KV + 31) / 32;
    for (int kr = 0; kr < KR; ++kr){
      const int kc = kr * 32;
      __syncthreads();
      if (NT == 8){
        int n = tid >> 1, kb = (tid & 1) * 16;
        uint4 z = {0,0,0,0}; uint4 v0 = z, v1 = z;
        if (kb < KV)     v0 = *(const uint4*)(BT + (size_t)(cbase + n) * KV + kc + kb);
        if (kb + 8 < KV) v1 = *(const uint4*)(BT + (size_t)(cbase + n) * KV + kc + kb + 8);
        *(uint4*)&Bst[n * 40 + kb] = v0;
        *(uint4*)&Bst[n * 40 + kb + 8] = v1;
      } else {
        int n = tid >> 2, kb = (tid & 3) * 8;
        uint4 v = *(const uint4*)(BT + (size_t)n * KV + kc + kb);
        *(uint4*)&Bst[n * 40 + kb] = v;
      }
      short8 a0 = {0,0,0,0,0,0,0,0}, a1 = {0,0,0,0,0,0,0,0};
      if (KV >= 32 || q < 2){
        a0 = *(const short8*)(Pin + (size_t)(g * 128 + 16 * w       + r) * KV + kc + q * 8);
        a1 = *(const short8*)(Pin + (size_t)(g * 128 + 16 * (w + 4) + r) * KV + kc + q * 8);
      }
      __syncthreads();
      for (int nt = 0; nt < NT; ++nt){
        short8 bf = *(const short8*)&Bst[(16 * nt + r) * 40 + q * 8];
        acc0[nt] = __builtin_amdgcn_mfma_f32_16x16x32_bf16(a0, bf, acc0[nt], 0, 0, 0);
        acc1[nt] = __builtin_amdgcn_mfma_f32_16x16x32_bf16(a1, bf, acc1[nt], 0, 0, 0);
      }
    }
    __syncthreads();
    for (int nt = 0; nt < NT; ++nt)
      #pragma unroll
      for (int i = 0; i < 4; ++i){
        HT_[(16 * nt + r) * 136 + 16 * w       + q * 4 + i] = f2b(acc0[nt][i]);
        HT_[(16 * nt + r) * 136 + 16 * (w + 4) + q * 4 + i] = f2b(acc1[nt][i]);
      }
    __syncthreads();
  };

  // ---- MFMA aggregation for one head: alpha-dense(AD) @ HT_ cols [colbase..colbase+64) ----
  // scatter phase fills AD; returns per-lane acc in am[2][4]; caller does epilogue.
  auto agg_head = [&](int hl, int colbase, float4v am[2][4]){
    #pragma unroll
    for (int mt = 0; mt < 2; ++mt)
      #pragma unroll
      for (int nt = 0; nt < 4; ++nt) am[mt][nt] = (float4v){0,0,0,0};
    #pragma unroll
    for (int kc = 0; kc < 4; ++kc){
      short8 af0 = *(const short8*)&AD[(w * 32      + r) * 136 + kc * 32 + q * 8];
      short8 af1 = *(const short8*)&AD[(w * 32 + 16 + r) * 136 + kc * 32 + q * 8];
      #pragma unroll
      for (int nt = 0; nt < 4; ++nt){
        short8 bf = *(const short8*)&HT_[(colbase + nt * 16 + r) * 136 + kc * 32 + q * 8];
        am[0][nt] = __builtin_amdgcn_mfma_f32_16x16x32_bf16(af0, bf, am[0][nt], 0, 0, 0);
        am[1][nt] = __builtin_amdgcn_mfma_f32_16x16x32_bf16(af1, bf, am[1][nt], 0, 0, 0);
      }
    }
  };

  auto sync_partner = [&](int* FLx){
    __syncthreads();
    if (tid == 0){
      __hip_atomic_store(&FLx[blockIdx.x], 1, __ATOMIC_RELEASE, __HIP_MEMORY_SCOPE_AGENT);
      int guard = 0;
      while (__hip_atomic_load(&FLx[blockIdx.x ^ 1], __ATOMIC_ACQUIRE,
                               __HIP_MEMORY_SCOPE_AGENT) == 0 && guard < 200000){
        __builtin_amdgcn_s_sleep(1);
        ++guard;
      }
    }
    __syncthreads();
  };

  // ---- 4-head half-layer (L0/L1): GEMM^T + attn + per-head dense-softmax + MFMA agg ----
  auto do_layer = [&](int KV, const unsigned short* Pin, const unsigned short* BT,
                      int asoff, int adoff, int boff, unsigned short* Pout){
    gemm_T(KV, 8, Pin, BT);
    { // attention logits (2 local heads)
      float as0 = Wbuf[asoff + c0 + 2 * lane], as1 = Wbuf[asoff + c0 + 2 * lane + 1];
      float ad0 = Wbuf[adoff + c0 + 2 * lane], ad1 = Wbuf[adoff + c0 + 2 * lane + 1];
      for (int it = 0; it < 32; ++it){
        int n = it * 4 + w;
        float e0 = b2f(HT_[(2 * lane) * 136 + n]);
        float e1 = b2f(HT_[(2 * lane + 1) * 136 + n]);
        float vs = e0 * as0 + e1 * as1;
        float vd = e0 * ad0 + e1 * ad1;
        #pragma unroll
        for (int m = 16; m >= 1; m >>= 1){ vs += __shfl_xor(vs, m); vd += __shfl_xor(vd, m); }
        if ((lane & 31) == 0){
          ALS16[n * 2 + (lane >> 5)] = f2h(vs);
          ALD16[n * 2 + (lane >> 5)] = f2h(vd);
        }
      }
    }
    __syncthreads();
    for (int hl = 0; hl < 2; ++hl){
      for (int i = tid; i < 8704; i += 256) ((unsigned int*)AD)[i] = 0;
      __syncthreads();
      if (tid < 128){
        int n = tid;
        float aldv = h2f(ALD16[n * 2 + hl]);
        int rs = rowL[n], re = rowL[n + 1];
        float mx = -3e38f, den = 0.f;
        for (int j = rs; j < re; ++j){
          float v = h2f(ALS16[srcL[j] * 2 + hl]) + aldv;
          v = v > 0.f ? v : 0.2f * v;
          if (v > mx){ den = den * __expf(mx - v) + 1.f; mx = v; }
          else den += __expf(v - mx);
        }
        float iden = 1.f / (den + 1e-16f);
        for (int j = rs; j < re; ++j){
          float v = h2f(ALS16[srcL[j] * 2 + hl]) + aldv;
          v = v > 0.f ? v : 0.2f * v;
          float al = __expf(v - mx) * iden;
          int s = srcL[j];
          AD[n * 136 + s] = f2b(b2f(AD[n * 136 + s]) + al);   // accumulate (duplicate edges)
        }
      }
      __syncthreads();
      float4v am[2][4];
      agg_head(hl, hl * 64, am);
      #pragma unroll
      for (int mt = 0; mt < 2; ++mt)
        #pragma unroll
        for (int nt = 0; nt < 4; ++nt){
          int col = hl * 64 + nt * 16 + r;
          float bz = Wbuf[boff + c0 + col];
          #pragma unroll
          for (int i = 0; i < 4; ++i){
            int dst = w * 32 + mt * 16 + q * 4 + i;
            float v = am[mt][nt][i] + bz;
            v = v > 0.f ? v : 0.f;
            __hip_atomic_store((unsigned short*)&Pout[(size_t)(g * 128 + dst) * 256 + c0 + col],
                               f2b(v), __ATOMIC_RELAXED, __HIP_MEMORY_SCOPE_AGENT);
          }
        }
      __syncthreads();   // AD reuse fence for next head
    }
  };

  //======== Layer 0 / Layer 1 ========
  do_layer(16, Pb, BBF + BOFF_G0, WOFF_G0AS, WOFF_G0AD, WOFF_G0B, PA);
  sync_partner(FL);
  do_layer(256, PA, BBF + BOFF_G1, WOFF_G1AS, WOFF_G1AD, WOFF_G1B, PB);
  sync_partner(FL + 512);

  //======== Layer 2 (1 head, 64 cols; duplicated across half-blocks, pool split) ========
  {
    gemm_T(256, 4, PB, BBF + BOFF_G2);
    { // attention (64 cols)
      float asv = Wbuf[WOFF_G2AS + lane];
      float adv = Wbuf[WOFF_G2AD + lane];
      for (int it = 0; it < 32; ++it){
        int n = it * 4 + w;
        float e0 = b2f(HT_[lane * 136 + n]);
        float vs = e0 * asv, vd = e0 * adv;
        #pragma unroll
        for (int m = 32; m >= 1; m >>= 1){ vs += __shfl_xor(vs, m); vd += __shfl_xor(vd, m); }
        if (lane == 0){ ALSf[n] = vs; ALDf[n] = vd; }
      }
    }
    __syncthreads();
    for (int i = tid; i < 8704; i += 256) ((unsigned int*)AD)[i] = 0;
    __syncthreads();
    if (tid < 128){
      int n = tid;
      float aldv = ALDf[n];
      int rs = rowL[n], re = rowL[n + 1];
      float mx = -3e38f, den = 0.f;
      for (int j = rs; j < re; ++j){
        float v = ALSf[srcL[j]] + aldv;
        v = v > 0.f ? v : 0.2f * v;
        if (v > mx){ den = den * __expf(mx - v) + 1.f; mx = v; }
        else den += __expf(v - mx);
      }
      float iden = 1.f / (den + 1e-16f);
      for (int j = rs; j < re; ++j){
        float v = ALSf[srcL[j]] + aldv;
        v = v > 0.f ? v : 0.2f * v;
        float al = __expf(v - mx) * iden;
        int s = srcL[j];
        AD[n * 136 + s] = f2b(b2f(AD[n * 136 + s]) + al);
      }
    }
    __syncthreads();
    float4v am[2][4];
    agg_head(0, 0, am);
    float psum[4] = {0.f, 0.f, 0.f, 0.f};
    #pragma unroll
    for (int nt = 0; nt < 4; ++nt){
      int col = nt * 16 + r;
      float bz = Wbuf[WOFF_G2B + col];
      #pragma unroll
      for (int mt = 0; mt < 2; ++mt)
        #pragma unroll
        for (int i = 0; i < 4; ++i){
          float v = am[mt][nt][i] + bz;
          psum[nt] += (v > 0.f ? v : 0.f);
        }
      psum[nt] += __shfl_xor(psum[nt], 16);
      psum[nt] += __shfl_xor(psum[nt], 32);
    }
    if (q == 0){
      #pragma unroll
      for (int nt = 0; nt < 4; ++nt) pools[w][nt * 16 + r] = psum[nt];
    }
    __syncthreads();
    if (tid < 64 && (tid >> 5) == hb){
      float s = pools[0][tid] + pools[1][tid] + pools[2][tid] + pools[3][tid];
      int b = g >> 6, tq = g & 63;
      XSEQ[(size_t)(tq * BSZ + b) * HIDD + tid] = f2b(s);
    }
  }
}

// ---------------- MFMA matmul for BOTH Wih GEMMs in one launch (z = dir) ----------------
__global__ __launch_bounds__(256)
void mmx2_kernel(const unsigned short* __restrict__ A,
                 const unsigned short* __restrict__ B0, const unsigned short* __restrict__ B1,
                 float* __restrict__ C0, float* __restrict__ C1, int M, int Nc, int K)
{
  __shared__ unsigned short As[64][40];
  __shared__ unsigned short Bs[64][40];
  const unsigned short* Bb = blockIdx.z ? B1 : B0;
  float* C = blockIdx.z ? C1 : C0;
  const int tid = threadIdx.x;
  const int w = tid >> 6, lane = tid & 63, q = lane >> 4, r = lane & 15;
  const int m0 = blockIdx.x * 64, n0 = blockIdx.y * 64;
  float4v acc0 = {0,0,0,0}, acc1 = {0,0,0,0}, acc2 = {0,0,0,0}, acc3 = {0,0,0,0};
  const int arow = tid >> 2, akb = (tid & 3) * 8;
  const int bk = tid >> 3, bnb = (tid & 7) * 8;
  for (int kc = 0; kc < K; kc += 32){
    int kw = K - kc; if (kw > 32) kw = 32;
    if (akb < kw){
      uint4 v = *(const uint4*)(A + (size_t)(m0 + arow) * K + kc + akb);
      *(uint4*)&As[arow][akb] = v;
    } else {
      uint4 z = {0,0,0,0}; *(uint4*)&As[arow][akb] = z;
    }
    if (bk < kw){
      uint4 v = *(const uint4*)(Bb + (size_t)(kc + bk) * Nc + n0 + bnb);
      const unsigned short* vs = (const unsigned short*)&v;
      #pragma unroll
      for (int e = 0; e < 8; ++e) Bs[bnb + e][bk] = vs[e];
    } else {
      #pragma unroll
      for (int e = 0; e < 8; ++e) Bs[bnb + e][bk] = 0;
    }
    __syncthreads();
    short8 af = *(const short8*)&As[16 * w + r][q * 8];
    short8 b0 = *(const short8*)&Bs[r][q * 8];
    short8 b1 = *(const short8*)&Bs[16 + r][q * 8];
    short8 b2 = *(const short8*)&Bs[32 + r][q * 8];
    short8 b3 = *(const short8*)&Bs[48 + r][q * 8];
    acc0 = __builtin_amdgcn_mfma_f32_16x16x32_bf16(af, b0, acc0, 0, 0, 0);
    acc1 = __builtin_amdgcn_mfma_f32_16x16x32_bf16(af, b1, acc1, 0, 0, 0);
    acc2 = __builtin_amdgcn_mfma_f32_16x16x32_bf16(af, b2, acc2, 0, 0, 0);
    acc3 = __builtin_amdgcn_mfma_f32_16x16x32_bf16(af, b3, acc3, 0, 0, 0);
    __syncthreads();
  }
  const int row = m0 + 16 * w + q * 4, col0 = n0 + r;
  #pragma unroll
  for (int i = 0; i < 4; ++i){
    size_t base = (size_t)(row + i) * Nc;
    C[base + col0]      = acc0[i];
    C[base + col0 + 16] = acc1[i];
    C[base + col0 + 32] = acc2[i];
    C[base + col0 + 48] = acc3[i];
  }
}

// ---------------- LSTM via MFMA: 8 WGs, sentinel sync; H16 rows padded (132 uints) ----------------
__global__ __launch_bounds__(256)
void lstm13_kernel(const float* __restrict__ XF, const float* __restrict__ XB,
                   const unsigned int* __restrict__ WT,
                   const float* __restrict__ bih_f, const float* __restrict__ bhh_f,
                   const float* __restrict__ bih_b, const float* __restrict__ bhh_b,
                   unsigned int* __restrict__ HX,
                   float* __restrict__ HT)
{
  __shared__ unsigned int WL[32768];
  __shared__ unsigned int H16[16 * 132];
  __shared__ float glds[4][256];

  const int tid = threadIdx.x;
  const int m = blockIdx.x & 3, dir = blockIdx.x >> 2;
  const int w = tid >> 6, lane = tid & 63, quad = lane >> 4, r = lane & 15;
  const float* Xp = dir ? XB : XF;
  const int ub = tid >> 6, uj = tid & 63;
  unsigned int* HXd = HX + dir * 6144;

  const float* bi = dir ? bih_b : bih_f;
  const float* bh = dir ? bhh_b : bhh_f;
  float bias0 = bi[0 * 256 + 64 * m + uj] + bh[0 * 256 + 64 * m + uj];
  float bias1 = bi[1 * 256 + 64 * m + uj] + bh[1 * 256 + 64 * m + uj];
  float bias2 = bi[2 * 256 + 64 * m + uj] + bh[2 * 256 + 64 * m + uj];
  float bias3 = bi[3 * 256 + 64 * m + uj] + bh[3 * 256 + 64 * m + uj];

  {
    const uint4* WT4 = (const uint4*)(WT + dir * 131072 + m * 32768);
    uint4* WL4 = (uint4*)WL;
    #pragma unroll
    for (int s = 0; s < 32; ++s)
      WL4[s * 256 + tid] = WT4[s * 256 + tid];
  }
  for (int i = tid; i < 16 * 132; i += 256) H16[i] = 0;
  float c = 0.f;
  __syncthreads();

  const uint4* WL4 = (const uint4*)WL;
  const uint4* H16u4 = (const uint4*)H16;

  float4v acc[4];
  auto kchunk = [&](int kc){
    uint4 av = H16u4[(lane & 15) * 33 + kc * 4 + quad];
    short8 af = *(const short8*)&av;
    #pragma unroll
    for (int t = 0; t < 4; ++t){
      int nt = w * 4 + t;
      uint4 bv = WL4[(kc * 16 + nt) * 64 + lane];
      short8 bf = *(const short8*)&bv;
      acc[t] = __builtin_amdgcn_mfma_f32_16x16x32_bf16(af, bf, acc[t], 0, 0, 0);
    }
  };

  for (int t = 0; t < TT; ++t){
    const int tb = dir ? (TT - 1 - t) : t;
    const float* xr = Xp + (size_t)(tb * 4 + ub) * 1024 + 64 * m + uj;
    float x0 = xr[0], x1 = xr[256], x2 = xr[512], x3 = xr[768];

    #pragma unroll
    for (int i = 0; i < 4; ++i) acc[i] = (float4v){0,0,0,0};
    kchunk(2 * m); kchunk(2 * m + 1);
    if (t > 0 && w > 0){
      int qp = (m + w) & 3;
      unsigned int* S = HXd + ((t - 1) % 3) * 2048 + m * 512;
      int b2 = lane >> 5, p2 = lane & 31;
      int i1G = b2 * 128 + 32 * qp + p2;
      int i2G = (b2 + 2) * 128 + 32 * qp + p2;
      int i1L = b2 * 132 + 32 * qp + p2;
      int i2L = (b2 + 2) * 132 + 32 * qp + p2;
      unsigned int v1, v2;
      int guard = 0;
      while ((v1 = __hip_atomic_load(&S[i1G], __ATOMIC_RELAXED, __HIP_MEMORY_SCOPE_AGENT)) == SENT
             && guard < 200000){ __builtin_amdgcn_s_sleep(1); ++guard; }
      guard = 0;
      while ((v2 = __hip_atomic_load(&S[i2G], __ATOMIC_RELAXED, __HIP_MEMORY_SCOPE_AGENT)) == SENT
             && guard < 200000){ __builtin_amdgcn_s_sleep(1); ++guard; }
      H16[i1L] = v1; H16[i2L] = v2;
      __hip_atomic_store(&S[i1G], SENT, __ATOMIC_RELAXED, __HIP_MEMORY_SCOPE_AGENT);
      __hip_atomic_store(&S[i2G], SENT, __ATOMIC_RELAXED, __HIP_MEMORY_SCOPE_AGENT);
    }
    __syncthreads();
    #pragma unroll
    for (int i = 1; i < 4; ++i){
      int qp = (m + i) & 3;
      kchunk(2 * qp); kchunk(2 * qp + 1);
    }
    if (quad == 0){
      #pragma unroll
      for (int tt = 0; tt < 4; ++tt){
        int l = (w * 4 + tt) * 16 + r;
        glds[0][l] = acc[tt][0];
        glds[1][l] = acc[tt][1];
        glds[2][l] = acc[tt][2];
        glds[3][l] = acc[tt][3];
      }
    }
    __syncthreads();

    float gi = glds[ub][uj]        + bias0 + x0;
    float gf = glds[ub][64 + uj]   + bias1 + x1;
    float gg = glds[ub][128 + uj]  + bias2 + x2;
    float go = glds[ub][192 + uj]  + bias3 + x3;
    float si = 1.f / (1.f + __expf(-gi));
    float sf = 1.f / (1.f + __expf(-gf));
    float so = 1.f / (1.f + __expf(-go));
    float tg = 1.f - 2.f / (1.f + __expf(2.f * gg));
    c = sf * c + si * tg;
    float ch = 1.f - 2.f / (1.f + __expf(2.f * c));
    float hval = so * ch;
    if (t == TT - 1){
      HT[(size_t)(dir * 4 + ub) * RHID + (64 * m + uj)] = hval;
      break;
    }
    unsigned int own = f2b(hval);
    unsigned int partner = ((unsigned int)__shfl_xor((int)own, 1)) & 0xffffu;
    unsigned int* S = HXd + (t % 3) * 2048;
    if ((uj & 1) == 0){
      unsigned int v = own | (partner << 16);
      int p = uj >> 1;
      int idxG = ub * 128 + 32 * m + p;
      int idxL = ub * 132 + 32 * m + p;
      H16[idxL] = v;
      #pragma unroll
      for (int cns = 1; cns < 4; ++cns)
        __hip_atomic_store(&S[((m + cns) & 3) * 512 + idxG], v,
                           __ATOMIC_RELAXED, __HIP_MEMORY_SCOPE_AGENT);
    }
    __syncthreads();
  }
}

// ---------------- heads + Poincare projection, fp32 out ----------------
__global__ __launch_bounds__(512)
void head2_kernel(const float* __restrict__ HT,
                  const float* __restrict__ muW, const float* __restrict__ mub,
                  const float* __restrict__ lvW, const float* __restrict__ lvb,
                  float* __restrict__ out)
{
  __shared__ float feat[4][512];
  __shared__ float muv[4][64];
  __shared__ float lvv[4][64];
  int tid = threadIdx.x;
  for (int i = tid; i < 2048; i += 512){
    int rr = i >> 8, k = i & 255;
    int b = rr & 3, d = rr >> 2;
    feat[b][d * 256 + k] = HT[i];
  }
  __syncthreads();
  int w = tid >> 6, lane = tid & 63;
  for (int job = w; job < 512; job += 8){
    int j = job & 63, b = (job >> 6) & 3, mat = job >> 8;
    const float* W = (mat ? lvW : muW) + (size_t)j * 512;
    float s = 0.f;
    #pragma unroll
    for (int e = 0; e < 8; ++e) s += W[lane * 8 + e] * feat[b][lane * 8 + e];
    #pragma unroll
    for (int mm = 32; mm >= 1; mm >>= 1) s += __shfl_xor(s, mm);
    if (lane == 0){
      float v = s + (mat ? lvb[j] : mub[j]);
      if (mat) lvv[b][j] = v; else muv[b][j] = v;
    }
  }
  __syncthreads();
  if (tid < 256){
    int b = tid >> 6, j = tid & 63;
    float mu = muv[b][j];
    float sq = mu * mu;
    #pragma unroll
    for (int mm = 32; mm >= 1; mm >>= 1) sq += __shfl_xor(sq, mm);
    float nrm = sqrtf(sq);
    const float mxn = 1.0f - 4e-3f;
    if (nrm > mxn) mu = mu / nrm * mxn;
    out[b * 64 + j] = mu;
    out[256 + b * 64 + j] = lvv[b][j];
  }
}

extern "C" void kernel_launch(void* const* d_in, const int* in_sizes, int n_in,
                              void* d_out, int out_size, void* d_ws, size_t ws_size,
                              hipStream_t stream)
{
  const int* ei = (const int*)d_in[1];

  float* FW   = (float*)d_ws;
  float* Wbuf = FW + FOFF_WBUF;
  int*   csr_row = (int*)(FW + FOFF_CSR);
  unsigned short* csr_src = (unsigned short*)(FW + FOFF_CSR + 132);
  int*   FL   = (int*)(FW + FOFF_CSR + 1024);
  float* XFp  = FW + FOFF_XFP;
  float* XBp  = FW + FOFF_XBP;
  float* HT   = FW + FOFF_HT;
  unsigned short* XSEQ = (unsigned short*)(FW + FOFF_XSEQ);
  unsigned short* PA   = (unsigned short*)(FW + FOFF_PA);
  unsigned short* PB   = (unsigned short*)(FW + FOFF_PB);
  unsigned short* Pb   = (unsigned short*)(FW + FOFF_P);
  unsigned int*   WT   = (unsigned int*)(FW + FOFF_WE);
  unsigned short* BBF  = (unsigned short*)(FW + FOFF_BBF);
  unsigned int*   HX   = (unsigned int*)(FW + FOFF_SYNC);

  CvtArgs ca;
  static const int wsz[24] = {4096,256,256,256, 65536,256,256,256, 16384,64,64,64,
                              65536,262144,1024,1024, 65536,262144,1024,1024,
                              32768,64,32768,64};
  {
    int acc = 0;
    for (int k = 0; k < 24; ++k){ ca.src[k] = d_in[2 + k]; ca.off[k] = acc; acc += wsz[k]; }
    ca.off[24] = acc;
  }
  int nblk = (SP_TOTAL + 255) / 256 + 1;
  setup_kernel<<<nblk, 256, 0, stream>>>(ca, Wbuf, BBF, Pb, WT, HX, FL,
                                         d_in[0], ei, csr_row, csr_src);

  gat3_kernel<<<512, 256, 0, stream>>>(Pb, BBF, Wbuf, csr_row, csr_src, PA, PB, XSEQ, FL);

  mmx2_kernel<<<dim3(4, 16, 2), 256, 0, stream>>>(XSEQ, BBF + BOFF_WF, BBF + BOFF_WB,
                                                  XFp, XBp, 256, 1024, 64);

  lstm13_kernel<<<8, 256, 0, stream>>>(XFp, XBp, WT,
                                       Wbuf + WOFF_BIHF, Wbuf + WOFF_BHHF,
                                       Wbuf + WOFF_BIHB, Wbuf + WOFF_BHHB,
                                       HX, HT);

  head2_kernel<<<1, 512, 0, stream>>>(HT, Wbuf + WOFF_MUW, Wbuf + WOFF_MUB,
                                      Wbuf + WOFF_LVW, Wbuf + WOFF_LVB, (float*)d_out);
}

// Round 21
// 360.823 us; speedup vs baseline: 1.4404x; 1.0684x over previous
//
#include <hip/hip_runtime.h>
#include <hip/hip_bf16.h>

// ---- problem constants ----
#define BSZ 4
#define TT 64
#define NNODE 128
#define NFEAT 16
#define HIDD 64
#define NHEAD 4
#define RHID 256
#define LDIM 64
#define EPG 1024
#define NGRAPH (BSZ*TT)          // 256
#define NTOT (NGRAPH*NNODE)      // 32768
#define ESLOTS (EPG+NNODE)       // 1152

// ---- canonical fp32 weight buffer offsets (floats) ----
#define WOFF_G0W 0
#define WOFF_G0AS 4096
#define WOFF_G0AD 4352
#define WOFF_G0B 4608
#define WOFF_G1W 4864
#define WOFF_G1AS 70400
#define WOFF_G1AD 70656
#define WOFF_G1B 70912
#define WOFF_G2W 71168
#define WOFF_G2AS 87552
#define WOFF_G2AD 87616
#define WOFF_G2B 87680
#define WOFF_WIHF 87744
#define WOFF_WHHF 153280
#define WOFF_BIHF 415424
#define WOFF_BHHF 416448
#define WOFF_WIHB 417472
#define WOFF_WHHB 483008
#define WOFF_BIHB 745152
#define WOFF_BHHB 746176
#define WOFF_MUW 747200
#define WOFF_MUB 779968
#define WOFF_LVW 780032
#define WOFF_LVB 812800
#define WTOTAL   812864

// ---- workspace float offsets ----
#define FOFF_WBUF 4096
#define FOFF_CSR  1052672      // csr_row int[132], csr_src u16[1152]
#define FOFF_SYNC 1314816      // HX: 2*3*4*512 uints (sentinel protocol)
#define FOFF_WE   1576960      // WTB (bf16 B-frag Whh, 262144 uints)
#define FOFF_BBF  1900000      // bf16 B matrices (u16 view)
#define FOFF_XFP  2756608
#define FOFF_XBP  3018752
#define FOFF_HT   3280896
#define FOFF_XSEQ 3282944
#define FOFF_PA   3291136      // P0 [32768][256] bf16
#define FOFF_PB   5388288      // P1 [32768][256] bf16
#define FOFF_P    7485440      // X  [32768][16]  bf16

// bf16 B-matrix u16 offsets inside BBF (G0/G1/G2 stored TRANSPOSED [out][in])
#define BOFF_G0 0
#define BOFF_G1 4096
#define BOFF_G2 69632
#define BOFF_WF 86016
#define BOFF_WB 151552
#define BTOTAL  217088

// setup phases
#define SP_CVTX  (WTOTAL + BTOTAL)            // 1029952
#define SP_WHH   (SP_CVTX + NTOT*NFEAT)       // 1554240
#define SP_HX    (SP_WHH + 262144)            // 1816384
#define SP_TOTAL (SP_HX + 12288)              // 1828672

#define SENT 0xFFFFFFFFu

typedef __attribute__((ext_vector_type(8))) short short8;
typedef __attribute__((ext_vector_type(4))) float float4v;

__device__ __forceinline__ float b2f(unsigned short u){
  union { unsigned int i; float f; } v; v.i = ((unsigned int)u) << 16; return v.f;
}
__device__ __forceinline__ unsigned short f2b(float f){
  __hip_bfloat16 h = __float2bfloat16(f);
  union { __hip_bfloat16 h; unsigned short u; } v; v.h = h; return v.u;
}
__device__ __forceinline__ float ldf(const void* p, int i, int flag){
  return flag ? b2f(((const unsigned short*)p)[i]) : ((const float*)p)[i];
}
__device__ __forceinline__ float h2f(unsigned short s){
  union { _Float16 hh; unsigned short s; } u; u.s = s; return (float)u.hh;
}
__device__ __forceinline__ unsigned short f2h(float f){
  union { _Float16 hh; unsigned short s; } u; u.hh = (_Float16)f; return u.s;
}
__device__ __forceinline__ int sniff32(const unsigned short* w){
  int ok = 0;
  #pragma unroll
  for (int i = 0; i < 32; ++i){
    float a = fabsf(b2f(w[2 * i]));
    if (a > 1e-8f && a < 4.f) ok++;
  }
  return ok >= 16 ? 1 : 0;
}

// ---------------- fused setup: sniff + cvtw + packb(T) + cvtx + packwhh + HX + CSR ----------------
struct CvtArgs {
  const void* src[24];
  int off[25];
};
__global__ void setup_kernel(CvtArgs a,
                             float* __restrict__ W, unsigned short* __restrict__ BBF,
                             unsigned short* __restrict__ P, unsigned int* __restrict__ WT,
                             unsigned int* __restrict__ HX,
                             const void* __restrict__ x, const int* __restrict__ ei,
                             int* __restrict__ csr_row, unsigned short* __restrict__ csr_src)
{
  __shared__ int cnt[NNODE];
  __shared__ int off[NNODE];
  __shared__ int wo[NNODE];
  const int tid = threadIdx.x;

  if (blockIdx.x == gridDim.x - 1){
    if (tid < NNODE) cnt[tid] = 0;
    __syncthreads();
    for (int i = tid; i < ESLOTS; i += 256){
      int d = (i < EPG) ? ei[EPG + i] : (i - EPG);
      atomicAdd(&cnt[d], 1);
    }
    __syncthreads();
    if (tid < NNODE) off[tid] = cnt[tid];
    for (int o = 1; o < NNODE; o <<= 1){
      __syncthreads();
      int t = (tid < NNODE && tid >= o) ? off[tid - o] : 0;
      __syncthreads();
      if (tid < NNODE) off[tid] += t;
    }
    __syncthreads();
    if (tid < NNODE){
      wo[tid] = off[tid] - cnt[tid];
      csr_row[tid + 1] = off[tid];
    }
    if (tid == 0) csr_row[0] = 0;
    __syncthreads();
    for (int i = tid; i < ESLOTS; i += 256){
      int s, d;
      if (i < EPG){ s = ei[i]; d = ei[EPG + i]; } else { s = i - EPG; d = i - EPG; }
      int pos = atomicAdd(&wo[d], 1);
      csr_src[pos] = (unsigned short)s;
    }
    return;
  }

  int id = blockIdx.x * blockDim.x + tid;
  if (id >= SP_TOTAL) return;
  int fl = sniff32((const unsigned short*)a.src[0]);
  if (id < WTOTAL){
    int k = 0;
    while (id >= a.off[k + 1]) ++k;
    W[id] = ldf(a.src[k], id - a.off[k], fl);
  } else if (id < WTOTAL + BTOTAL){
    int r = id - WTOTAL;
    float v;
    if (r < BOFF_G1){
      int o = r >> 4, k = r & 15;
      v = ldf(a.src[0], k * 256 + o, fl);
    } else if (r < BOFF_G2){
      int rr = r - BOFF_G1; int o = rr >> 8, k = rr & 255;
      v = ldf(a.src[4], k * 256 + o, fl);
    } else if (r < BOFF_WF){
      int rr = r - BOFF_G2; int o = rr >> 8, k = rr & 255;
      v = ldf(a.src[8], k * 64 + o, fl);
    } else if (r < BOFF_WB){
      int q = r - BOFF_WF; int k = q >> 10, n = q & 1023;
      v = ldf(a.src[12], n * 64 + k, fl);
    } else {
      int q = r - BOFF_WB; int k = q >> 10, n = q & 1023;
      v = ldf(a.src[16], n * 64 + k, fl);
    }
    BBF[r] = f2b(v);
  } else if (id < SP_CVTX + NTOT * NFEAT){
    int r = id - SP_CVTX;
    P[r] = fl ? ((const unsigned short*)x)[r] : f2b(((const float*)x)[r]);
  } else if (id < SP_HX){
    int r0 = id - SP_WHH;
    int c = r0 & 3;
    int lane = (r0 >> 2) & 63;
    int nt = (r0 >> 8) & 15;
    int kc = (r0 >> 12) & 7;
    int m = (r0 >> 15) & 3;
    int dir = r0 >> 17;
    int l = nt * 16 + (lane & 15);
    int u = (l >> 6) * 256 + 64 * m + (l & 63);
    int k0 = kc * 32 + ((lane >> 4) << 3) + 2 * c;
    const void* Wsrc = dir ? a.src[17] : a.src[13];
    unsigned short va = f2b(ldf(Wsrc, u * RHID + k0, fl));
    unsigned short vb = f2b(ldf(Wsrc, u * RHID + k0 + 1, fl));
    WT[r0] = (unsigned int)va | ((unsigned int)vb << 16);
  } else {
    HX[id - SP_HX] = SENT;
  }
}

// ---------------- GAT 4-head half-layer kernel (L0/L1): 512 blocks, MFMA agg, plain stores ----------------
template<int KV>
__global__ __launch_bounds__(256)
void glayer_kernel(const unsigned short* __restrict__ Pin,
                   const unsigned short* __restrict__ BT,
                   const float* __restrict__ Wbuf,
                   int asoff, int adoff, int boff,
                   const int* __restrict__ csr_row, const unsigned short* __restrict__ csr_src,
                   unsigned short* __restrict__ Pout)
{
  __shared__ unsigned short HT_[128 * 136];   // h^T [col][node]
  __shared__ unsigned short AD[128 * 136];    // union: Bst / dense-alpha [dst][src]
  __shared__ unsigned short ALS16[256];
  __shared__ unsigned short ALD16[256];
  __shared__ int   rowL[132];
  __shared__ unsigned char srcL[1152];

  const int tid = threadIdx.x;
  const int g = blockIdx.x >> 1, hb = blockIdx.x & 1;
  const int c0 = hb * 128;
  const int w = tid >> 6, lane = tid & 63, q = lane >> 4, r = lane & 15;
  unsigned short* Bst = AD;

  for (int i = tid; i < 129; i += 256) rowL[i] = csr_row[i];
  for (int i = tid; i < 1152; i += 256) srcL[i] = (unsigned char)csr_src[i];
  __syncthreads();

  // ---- GEMM producing h^T ----
  {
    float4v acc0[8], acc1[8];
    #pragma unroll
    for (int i = 0; i < 8; ++i){ acc0[i] = (float4v){0,0,0,0}; acc1[i] = (float4v){0,0,0,0}; }
    const int KR = (KV + 31) / 32;
    for (int kr = 0; kr < KR; ++kr){
      const int kc = kr * 32;
      __syncthreads();
      {
        int n = tid >> 1, kb = (tid & 1) * 16;
        uint4 z = {0,0,0,0}; uint4 v0 = z, v1 = z;
        if (kb < KV)     v0 = *(const uint4*)(BT + (size_t)(c0 + n) * KV + kc + kb);
        if (kb + 8 < KV) v1 = *(const uint4*)(BT + (size_t)(c0 + n) * KV + kc + kb + 8);
        *(uint4*)&Bst[n * 40 + kb] = v0;
        *(uint4*)&Bst[n * 40 + kb + 8] = v1;
      }
      short8 a0 = {0,0,0,0,0,0,0,0}, a1 = {0,0,0,0,0,0,0,0};
      if (KV >= 32 || q < 2){
        a0 = *(const short8*)(Pin + (size_t)(g * 128 + 16 * w       + r) * KV + kc + q * 8);
        a1 = *(const short8*)(Pin + (size_t)(g * 128 + 16 * (w + 4) + r) * KV + kc + q * 8);
      }
      __syncthreads();
      #pragma unroll
      for (int nt = 0; nt < 8; ++nt){
        short8 bf = *(const short8*)&Bst[(16 * nt + r) * 40 + q * 8];
        acc0[nt] = __builtin_amdgcn_mfma_f32_16x16x32_bf16(a0, bf, acc0[nt], 0, 0, 0);
        acc1[nt] = __builtin_amdgcn_mfma_f32_16x16x32_bf16(a1, bf, acc1[nt], 0, 0, 0);
      }
    }
    __syncthreads();
    #pragma unroll
    for (int nt = 0; nt < 8; ++nt)
      #pragma unroll
      for (int i = 0; i < 4; ++i){
        HT_[(16 * nt + r) * 136 + 16 * w       + q * 4 + i] = f2b(acc0[nt][i]);
        HT_[(16 * nt + r) * 136 + 16 * (w + 4) + q * 4 + i] = f2b(acc1[nt][i]);
      }
    __syncthreads();
  }

  // ---- attention logits (2 local heads) ----
  {
    float as0 = Wbuf[asoff + c0 + 2 * lane], as1 = Wbuf[asoff + c0 + 2 * lane + 1];
    float ad0 = Wbuf[adoff + c0 + 2 * lane], ad1 = Wbuf[adoff + c0 + 2 * lane + 1];
    for (int it = 0; it < 32; ++it){
      int n = it * 4 + w;
      float e0 = b2f(HT_[(2 * lane) * 136 + n]);
      float e1 = b2f(HT_[(2 * lane + 1) * 136 + n]);
      float vs = e0 * as0 + e1 * as1;
      float vd = e0 * ad0 + e1 * ad1;
      #pragma unroll
      for (int m = 16; m >= 1; m >>= 1){ vs += __shfl_xor(vs, m); vd += __shfl_xor(vd, m); }
      if ((lane & 31) == 0){
        ALS16[n * 2 + (lane >> 5)] = f2h(vs);
        ALD16[n * 2 + (lane >> 5)] = f2h(vd);
      }
    }
  }
  __syncthreads();

  // ---- per-head: dense softmax scatter + MFMA agg + plain-store epilogue ----
  for (int hl = 0; hl < 2; ++hl){
    for (int i = tid; i < 8704; i += 256) ((unsigned int*)AD)[i] = 0;
    __syncthreads();
    if (tid < 128){
      int n = tid;
      float aldv = h2f(ALD16[n * 2 + hl]);
      int rs = rowL[n], re = rowL[n + 1];
      float mx = -3e38f, den = 0.f;
      for (int j = rs; j < re; ++j){
        float v = h2f(ALS16[srcL[j] * 2 + hl]) + aldv;
        v = v > 0.f ? v : 0.2f * v;
        if (v > mx){ den = den * __expf(mx - v) + 1.f; mx = v; }
        else den += __expf(v - mx);
      }
      float iden = 1.f / (den + 1e-16f);
      for (int j = rs; j < re; ++j){
        float v = h2f(ALS16[srcL[j] * 2 + hl]) + aldv;
        v = v > 0.f ? v : 0.2f * v;
        float al = __expf(v - mx) * iden;
        int s = srcL[j];
        AD[n * 136 + s] = f2b(b2f(AD[n * 136 + s]) + al);
      }
    }
    __syncthreads();
    float4v am[2][4];
    #pragma unroll
    for (int mt = 0; mt < 2; ++mt)
      #pragma unroll
      for (int nt = 0; nt < 4; ++nt) am[mt][nt] = (float4v){0,0,0,0};
    #pragma unroll
    for (int kc = 0; kc < 4; ++kc){
      short8 af0 = *(const short8*)&AD[(w * 32      + r) * 136 + kc * 32 + q * 8];
      short8 af1 = *(const short8*)&AD[(w * 32 + 16 + r) * 136 + kc * 32 + q * 8];
      #pragma unroll
      for (int nt = 0; nt < 4; ++nt){
        short8 bf = *(const short8*)&HT_[(hl * 64 + nt * 16 + r) * 136 + kc * 32 + q * 8];
        am[0][nt] = __builtin_amdgcn_mfma_f32_16x16x32_bf16(af0, bf, am[0][nt], 0, 0, 0);
        am[1][nt] = __builtin_amdgcn_mfma_f32_16x16x32_bf16(af1, bf, am[1][nt], 0, 0, 0);
      }
    }
    #pragma unroll
    for (int mt = 0; mt < 2; ++mt)
      #pragma unroll
      for (int nt = 0; nt < 4; ++nt){
        int col = hl * 64 + nt * 16 + r;
        float bz = Wbuf[boff + c0 + col];
        #pragma unroll
        for (int i = 0; i < 4; ++i){
          int dst = w * 32 + mt * 16 + q * 4 + i;
          float v = am[mt][nt][i] + bz;
          v = v > 0.f ? v : 0.f;
          Pout[(size_t)(g * 128 + dst) * 256 + c0 + col] = f2b(v);
        }
      }
    __syncthreads();
  }
}

// ---------------- GAT layer 2 (1 head) + pool: 512 blocks ----------------
__global__ __launch_bounds__(256)
void glayer2_kernel(const unsigned short* __restrict__ Pin,
                    const unsigned short* __restrict__ BT,
                    const float* __restrict__ Wbuf,
                    const int* __restrict__ csr_row, const unsigned short* __restrict__ csr_src,
                    unsigned short* __restrict__ XSEQ)
{
  __shared__ unsigned short HT_[64 * 136];
  __shared__ unsigned short AD[128 * 136];
  __shared__ float ALSf[128];
  __shared__ float ALDf[128];
  __shared__ int   rowL[132];
  __shared__ unsigned char srcL[1152];
  __shared__ float pools[4][64];

  const int tid = threadIdx.x;
  const int g = blockIdx.x >> 1, hb = blockIdx.x & 1;
  const int w = tid >> 6, lane = tid & 63, q = lane >> 4, r = lane & 15;
  unsigned short* Bst = AD;

  for (int i = tid; i < 129; i += 256) rowL[i] = csr_row[i];
  for (int i = tid; i < 1152; i += 256) srcL[i] = (unsigned char)csr_src[i];
  __syncthreads();

  // ---- GEMM h2^T [64 cols][128 nodes] ----
  {
    float4v acc0[4], acc1[4];
    #pragma unroll
    for (int i = 0; i < 4; ++i){ acc0[i] = (float4v){0,0,0,0}; acc1[i] = (float4v){0,0,0,0}; }
    for (int kr = 0; kr < 8; ++kr){
      const int kc = kr * 32;
      __syncthreads();
      {
        int n = tid >> 2, kb = (tid & 3) * 8;
        uint4 v = *(const uint4*)(BT + (size_t)n * 256 + kc + kb);
        *(uint4*)&Bst[n * 40 + kb] = v;
      }
      short8 a0 = *(const short8*)(Pin + (size_t)(g * 128 + 16 * w       + r) * 256 + kc + q * 8);
      short8 a1 = *(const short8*)(Pin + (size_t)(g * 128 + 16 * (w + 4) + r) * 256 + kc + q * 8);
      __syncthreads();
      #pragma unroll
      for (int nt = 0; nt < 4; ++nt){
        short8 bf = *(const short8*)&Bst[(16 * nt + r) * 40 + q * 8];
        acc0[nt] = __builtin_amdgcn_mfma_f32_16x16x32_bf16(a0, bf, acc0[nt], 0, 0, 0);
        acc1[nt] = __builtin_amdgcn_mfma_f32_16x16x32_bf16(a1, bf, acc1[nt], 0, 0, 0);
      }
    }
    __syncthreads();
    #pragma unroll
    for (int nt = 0; nt < 4; ++nt)
      #pragma unroll
      for (int i = 0; i < 4; ++i){
        HT_[(16 * nt + r) * 136 + 16 * w       + q * 4 + i] = f2b(acc0[nt][i]);
        HT_[(16 * nt + r) * 136 + 16 * (w + 4) + q * 4 + i] = f2b(acc1[nt][i]);
      }
    __syncthreads();
  }

  // ---- attention (64 cols) ----
  {
    float asv = Wbuf[WOFF_G2AS + lane];
    float adv = Wbuf[WOFF_G2AD + lane];
    for (int it = 0; it < 32; ++it){
      int n = it * 4 + w;
      float e0 = b2f(HT_[lane * 136 + n]);
      float vs = e0 * asv, vd = e0 * adv;
      #pragma unroll
      for (int m = 32; m >= 1; m >>= 1){ vs += __shfl_xor(vs, m); vd += __shfl_xor(vd, m); }
      if (lane == 0){ ALSf[n] = vs; ALDf[n] = vd; }
    }
  }
  __syncthreads();
  for (int i = tid; i < 8704; i += 256) ((unsigned int*)AD)[i] = 0;
  __syncthreads();
  if (tid < 128){
    int n = tid;
    float aldv = ALDf[n];
    int rs = rowL[n], re = rowL[n + 1];
    float mx = -3e38f, den = 0.f;
    for (int j = rs; j < re; ++j){
      float v = ALSf[srcL[j]] + aldv;
      v = v > 0.f ? v : 0.2f * v;
      if (v > mx){ den = den * __expf(mx - v) + 1.f; mx = v; }
      else den += __expf(v - mx);
    }
    float iden = 1.f / (den + 1e-16f);
    for (int j = rs; j < re; ++j){
      float v = ALSf[srcL[j]] + aldv;
      v = v > 0.f ? v : 0.2f * v;
      float al = __expf(v - mx) * iden;
      int s = srcL[j];
      AD[n * 136 + s] = f2b(b2f(AD[n * 136 + s]) + al);
    }
  }
  __syncthreads();
  float4v am[2][4];
  #pragma unroll
  for (int mt = 0; mt < 2; ++mt)
    #pragma unroll
    for (int nt = 0; nt < 4; ++nt) am[mt][nt] = (float4v){0,0,0,0};
  #pragma unroll
  for (int kc = 0; kc < 4; ++kc){
    short8 af0 = *(const short8*)&AD[(w * 32      + r) * 136 + kc * 32 + q * 8];
    short8 af1 = *(const short8*)&AD[(w * 32 + 16 + r) * 136 + kc * 32 + q * 8];
    #pragma unroll
    for (int nt = 0; nt < 4; ++nt){
      short8 bf = *(const short8*)&HT_[(nt * 16 + r) * 136 + kc * 32 + q * 8];
      am[0][nt] = __builtin_amdgcn_mfma_f32_16x16x32_bf16(af0, bf, am[0][nt], 0, 0, 0);
      am[1][nt] = __builtin_amdgcn_mfma_f32_16x16x32_bf16(af1, bf, am[1][nt], 0, 0, 0);
    }
  }
  float psum[4] = {0.f, 0.f, 0.f, 0.f};
  #pragma unroll
  for (int nt = 0; nt < 4; ++nt){
    int col = nt * 16 + r;
    float bz = Wbuf[WOFF_G2B + col];
    #pragma unroll
    for (int mt = 0; mt < 2; ++mt)
      #pragma unroll
      for (int i = 0; i < 4; ++i){
        float v = am[mt][nt][i] + bz;
        psum[nt] += (v > 0.f ? v : 0.f);
      }
    psum[nt] += __shfl_xor(psum[nt], 16);
    psum[nt] += __shfl_xor(psum[nt], 32);
  }
  if (q == 0){
    #pragma unroll
    for (int nt = 0; nt < 4; ++nt) pools[w][nt * 16 + r] = psum[nt];
  }
  __syncthreads();
  if (tid < 64 && (tid >> 5) == hb){
    float s = pools[0][tid] + pools[1][tid] + pools[2][tid] + pools[3][tid];
    int b = g >> 6, tq = g & 63;
    XSEQ[(size_t)(tq * BSZ + b) * HIDD + tid] = f2b(s);
  }
}

// ---------------- MFMA matmul for BOTH Wih GEMMs in one launch (z = dir) ----------------
__global__ __launch_bounds__(256)
void mmx2_kernel(const unsigned short* __restrict__ A,
                 const unsigned short* __restrict__ B0, const unsigned short* __restrict__ B1,
                 float* __restrict__ C0, float* __restrict__ C1, int M, int Nc, int K)
{
  __shared__ unsigned short As[64][40];
  __shared__ unsigned short Bs[64][40];
  const unsigned short* Bb = blockIdx.z ? B1 : B0;
  float* C = blockIdx.z ? C1 : C0;
  const int tid = threadIdx.x;
  const int w = tid >> 6, lane = tid & 63, q = lane >> 4, r = lane & 15;
  const int m0 = blockIdx.x * 64, n0 = blockIdx.y * 64;
  float4v acc0 = {0,0,0,0}, acc1 = {0,0,0,0}, acc2 = {0,0,0,0}, acc3 = {0,0,0,0};
  const int arow = tid >> 2, akb = (tid & 3) * 8;
  const int bk = tid >> 3, bnb = (tid & 7) * 8;
  for (int kc = 0; kc < K; kc += 32){
    int kw = K - kc; if (kw > 32) kw = 32;
    if (akb < kw){
      uint4 v = *(const uint4*)(A + (size_t)(m0 + arow) * K + kc + akb);
      *(uint4*)&As[arow][akb] = v;
    } else {
      uint4 z = {0,0,0,0}; *(uint4*)&As[arow][akb] = z;
    }
    if (bk < kw){
      uint4 v = *(const uint4*)(Bb + (size_t)(kc + bk) * Nc + n0 + bnb);
      const unsigned short* vs = (const unsigned short*)&v;
      #pragma unroll
      for (int e = 0; e < 8; ++e) Bs[bnb + e][bk] = vs[e];
    } else {
      #pragma unroll
      for (int e = 0; e < 8; ++e) Bs[bnb + e][bk] = 0;
    }
    __syncthreads();
    short8 af = *(const short8*)&As[16 * w + r][q * 8];
    short8 b0 = *(const short8*)&Bs[r][q * 8];
    short8 b1 = *(const short8*)&Bs[16 + r][q * 8];
    short8 b2 = *(const short8*)&Bs[32 + r][q * 8];
    short8 b3 = *(const short8*)&Bs[48 + r][q * 8];
    acc0 = __builtin_amdgcn_mfma_f32_16x16x32_bf16(af, b0, acc0, 0, 0, 0);
    acc1 = __builtin_amdgcn_mfma_f32_16x16x32_bf16(af, b1, acc1, 0, 0, 0);
    acc2 = __builtin_amdgcn_mfma_f32_16x16x32_bf16(af, b2, acc2, 0, 0, 0);
    acc3 = __builtin_amdgcn_mfma_f32_16x16x32_bf16(af, b3, acc3, 0, 0, 0);
    __syncthreads();
  }
  const int row = m0 + 16 * w + q * 4, col0 = n0 + r;
  #pragma unroll
  for (int i = 0; i < 4; ++i){
    size_t base = (size_t)(row + i) * Nc;
    C[base + col0]      = acc0[i];
    C[base + col0 + 16] = acc1[i];
    C[base + col0 + 32] = acc2[i];
    C[base + col0 + 48] = acc3[i];
  }
}

// ---------------- LSTM via MFMA: 8 WGs, sentinel sync; H16 rows padded (132 uints) ----------------
__global__ __launch_bounds__(256)
void lstm13_kernel(const float* __restrict__ XF, const float* __restrict__ XB,
                   const unsigned int* __restrict__ WT,
                   const float* __restrict__ bih_f, const float* __restrict__ bhh_f,
                   const float* __restrict__ bih_b, const float* __restrict__ bhh_b,
                   unsigned int* __restrict__ HX,
                   float* __restrict__ HT)
{
  __shared__ unsigned int WL[32768];
  __shared__ unsigned int H16[16 * 132];
  __shared__ float glds[4][256];

  const int tid = threadIdx.x;
  const int m = blockIdx.x & 3, dir = blockIdx.x >> 2;
  const int w = tid >> 6, lane = tid & 63, quad = lane >> 4, r = lane & 15;
  const float* Xp = dir ? XB : XF;
  const int ub = tid >> 6, uj = tid & 63;
  unsigned int* HXd = HX + dir * 6144;

  const float* bi = dir ? bih_b : bih_f;
  const float* bh = dir ? bhh_b : bhh_f;
  float bias0 = bi[0 * 256 + 64 * m + uj] + bh[0 * 256 + 64 * m + uj];
  float bias1 = bi[1 * 256 + 64 * m + uj] + bh[1 * 256 + 64 * m + uj];
  float bias2 = bi[2 * 256 + 64 * m + uj] + bh[2 * 256 + 64 * m + uj];
  float bias3 = bi[3 * 256 + 64 * m + uj] + bh[3 * 256 + 64 * m + uj];

  {
    const uint4* WT4 = (const uint4*)(WT + dir * 131072 + m * 32768);
    uint4* WL4 = (uint4*)WL;
    #pragma unroll
    for (int s = 0; s < 32; ++s)
      WL4[s * 256 + tid] = WT4[s * 256 + tid];
  }
  for (int i = tid; i < 16 * 132; i += 256) H16[i] = 0;
  float c = 0.f;
  __syncthreads();

  const uint4* WL4 = (const uint4*)WL;
  const uint4* H16u4 = (const uint4*)H16;

  float4v acc[4];
  auto kchunk = [&](int kc){
    uint4 av = H16u4[(lane & 15) * 33 + kc * 4 + quad];
    short8 af = *(const short8*)&av;
    #pragma unroll
    for (int t = 0; t < 4; ++t){
      int nt = w * 4 + t;
      uint4 bv = WL4[(kc * 16 + nt) * 64 + lane];
      short8 bf = *(const short8*)&bv;
      acc[t] = __builtin_amdgcn_mfma_f32_16x16x32_bf16(af, bf, acc[t], 0, 0, 0);
    }
  };

  for (int t = 0; t < TT; ++t){
    const int tb = dir ? (TT - 1 - t) : t;
    const float* xr = Xp + (size_t)(tb * 4 + ub) * 1024 + 64 * m + uj;
    float x0 = xr[0], x1 = xr[256], x2 = xr[512], x3 = xr[768];

    #pragma unroll
    for (int i = 0; i < 4; ++i) acc[i] = (float4v){0,0,0,0};
    kchunk(2 * m); kchunk(2 * m + 1);
    if (t > 0 && w > 0){
      int qp = (m + w) & 3;
      unsigned int* S = HXd + ((t - 1) % 3) * 2048 + m * 512;
      int b2 = lane >> 5, p2 = lane & 31;
      int i1G = b2 * 128 + 32 * qp + p2;
      int i2G = (b2 + 2) * 128 + 32 * qp + p2;
      int i1L = b2 * 132 + 32 * qp + p2;
      int i2L = (b2 + 2) * 132 + 32 * qp + p2;
      unsigned int v1, v2;
      int guard = 0;
      while ((v1 = __hip_atomic_load(&S[i1G], __ATOMIC_RELAXED, __HIP_MEMORY_SCOPE_AGENT)) == SENT
             && guard < 200000){ __builtin_amdgcn_s_sleep(1); ++guard; }
      guard = 0;
      while ((v2 = __hip_atomic_load(&S[i2G], __ATOMIC_RELAXED, __HIP_MEMORY_SCOPE_AGENT)) == SENT
             && guard < 200000){ __builtin_amdgcn_s_sleep(1); ++guard; }
      H16[i1L] = v1; H16[i2L] = v2;
      __hip_atomic_store(&S[i1G], SENT, __ATOMIC_RELAXED, __HIP_MEMORY_SCOPE_AGENT);
      __hip_atomic_store(&S[i2G], SENT, __ATOMIC_RELAXED, __HIP_MEMORY_SCOPE_AGENT);
    }
    __syncthreads();
    #pragma unroll
    for (int i = 1; i < 4; ++i){
      int qp = (m + i) & 3;
      kchunk(2 * qp); kchunk(2 * qp + 1);
    }
    if (quad == 0){
      #pragma unroll
      for (int tt = 0; tt < 4; ++tt){
        int l = (w * 4 + tt) * 16 + r;
        glds[0][l] = acc[tt][0];
        glds[1][l] = acc[tt][1];
        glds[2][l] = acc[tt][2];
        glds[3][l] = acc[tt][3];
      }
    }
    __syncthreads();

    float gi = glds[ub][uj]        + bias0 + x0;
    float gf = glds[ub][64 + uj]   + bias1 + x1;
    float gg = glds[ub][128 + uj]  + bias2 + x2;
    float go = glds[ub][192 + uj]  + bias3 + x3;
    float si = 1.f / (1.f + __expf(-gi));
    float sf = 1.f / (1.f + __expf(-gf));
    float so = 1.f / (1.f + __expf(-go));
    float tg = 1.f - 2.f / (1.f + __expf(2.f * gg));
    c = sf * c + si * tg;
    float ch = 1.f - 2.f / (1.f + __expf(2.f * c));
    float hval = so * ch;
    if (t == TT - 1){
      HT[(size_t)(dir * 4 + ub) * RHID + (64 * m + uj)] = hval;
      break;
    }
    unsigned int own = f2b(hval);
    unsigned int partner = ((unsigned int)__shfl_xor((int)own, 1)) & 0xffffu;
    unsigned int* S = HXd + (t % 3) * 2048;
    if ((uj & 1) == 0){
      unsigned int v = own | (partner << 16);
      int p = uj >> 1;
      int idxG = ub * 128 + 32 * m + p;
      int idxL = ub * 132 + 32 * m + p;
      H16[idxL] = v;
      #pragma unroll
      for (int cns = 1; cns < 4; ++cns)
        __hip_atomic_store(&S[((m + cns) & 3) * 512 + idxG], v,
                           __ATOMIC_RELAXED, __HIP_MEMORY_SCOPE_AGENT);
    }
    __syncthreads();
  }
}

// ---------------- heads + Poincare projection, fp32 out ----------------
__global__ __launch_bounds__(512)
void head2_kernel(const float* __restrict__ HT,
                  const float* __restrict__ muW, const float* __restrict__ mub,
                  const float* __restrict__ lvW, const float* __restrict__ lvb,
                  float* __restrict__ out)
{
  __shared__ float feat[4][512];
  __shared__ float muv[4][64];
  __shared__ float lvv[4][64];
  int tid = threadIdx.x;
  for (int i = tid; i < 2048; i += 512){
    int rr = i >> 8, k = i & 255;
    int b = rr & 3, d = rr >> 2;
    feat[b][d * 256 + k] = HT[i];
  }
  __syncthreads();
  int w = tid >> 6, lane = tid & 63;
  for (int job = w; job < 512; job += 8){
    int j = job & 63, b = (job >> 6) & 3, mat = job >> 8;
    const float* W = (mat ? lvW : muW) + (size_t)j * 512;
    float s = 0.f;
    #pragma unroll
    for (int e = 0; e < 8; ++e) s += W[lane * 8 + e] * feat[b][lane * 8 + e];
    #pragma unroll
    for (int mm = 32; mm >= 1; mm >>= 1) s += __shfl_xor(s, mm);
    if (lane == 0){
      float v = s + (mat ? lvb[j] : mub[j]);
      if (mat) lvv[b][j] = v; else muv[b][j] = v;
    }
  }
  __syncthreads();
  if (tid < 256){
    int b = tid >> 6, j = tid & 63;
    float mu = muv[b][j];
    float sq = mu * mu;
    #pragma unroll
    for (int mm = 32; mm >= 1; mm >>= 1) sq += __shfl_xor(sq, mm);
    float nrm = sqrtf(sq);
    const float mxn = 1.0f - 4e-3f;
    if (nrm > mxn) mu = mu / nrm * mxn;
    out[b * 64 + j] = mu;
    out[256 + b * 64 + j] = lvv[b][j];
  }
}

extern "C" void kernel_launch(void* const* d_in, const int* in_sizes, int n_in,
                              void* d_out, int out_size, void* d_ws, size_t ws_size,
                              hipStream_t stream)
{
  const int* ei = (const int*)d_in[1];

  float* FW   = (float*)d_ws;
  float* Wbuf = FW + FOFF_WBUF;
  int*   csr_row = (int*)(FW + FOFF_CSR);
  unsigned short* csr_src = (unsigned short*)(FW + FOFF_CSR + 132);
  float* XFp  = FW + FOFF_XFP;
  float* XBp  = FW + FOFF_XBP;
  float* HT   = FW + FOFF_HT;
  unsigned short* XSEQ = (unsigned short*)(FW + FOFF_XSEQ);
  unsigned short* PA   = (unsigned short*)(FW + FOFF_PA);
  unsigned short* PB   = (unsigned short*)(FW + FOFF_PB);
  unsigned short* Pb   = (unsigned short*)(FW + FOFF_P);
  unsigned int*   WT   = (unsigned int*)(FW + FOFF_WE);
  unsigned short* BBF  = (unsigned short*)(FW + FOFF_BBF);
  unsigned int*   HX   = (unsigned int*)(FW + FOFF_SYNC);

  CvtArgs ca;
  static const int wsz[24] = {4096,256,256,256, 65536,256,256,256, 16384,64,64,64,
                              65536,262144,1024,1024, 65536,262144,1024,1024,
                              32768,64,32768,64};
  {
    int acc = 0;
    for (int k = 0; k < 24; ++k){ ca.src[k] = d_in[2 + k]; ca.off[k] = acc; acc += wsz[k]; }
    ca.off[24] = acc;
  }
  int nblk = (SP_TOTAL + 255) / 256 + 1;
  setup_kernel<<<nblk, 256, 0, stream>>>(ca, Wbuf, BBF, Pb, WT, HX,
                                         d_in[0], ei, csr_row, csr_src);

  // ---- GAT layers split for phase attribution (kernel boundary = coherence) ----
  glayer_kernel<16><<<512, 256, 0, stream>>>(Pb, BBF + BOFF_G0, Wbuf,
                                             WOFF_G0AS, WOFF_G0AD, WOFF_G0B,
                                             csr_row, csr_src, PA);
  glayer_kernel<256><<<512, 256, 0, stream>>>(PA, BBF + BOFF_G1, Wbuf,
                                              WOFF_G1AS, WOFF_G1AD, WOFF_G1B,
                                              csr_row, csr_src, PB);
  glayer2_kernel<<<512, 256, 0, stream>>>(PB, BBF + BOFF_G2, Wbuf,
                                          csr_row, csr_src, XSEQ);

  mmx2_kernel<<<dim3(4, 16, 2), 256, 0, stream>>>(XSEQ, BBF + BOFF_WF, BBF + BOFF_WB,
                                                  XFp, XBp, 256, 1024, 64);

  lstm13_kernel<<<8, 256, 0, stream>>>(XFp, XBp, WT,
                                       Wbuf + WOFF_BIHF, Wbuf + WOFF_BHHF,
                                       Wbuf + WOFF_BIHB, Wbuf + WOFF_BHHB,
                                       HX, HT);

  head2_kernel<<<1, 512, 0, stream>>>(HT, Wbuf + WOFF_MUW, Wbuf + WOFF_MUB,
                                      Wbuf + WOFF_LVW, Wbuf + WOFF_LVB, (float*)d_out);
}